// Round 1
// baseline (885.870 us; speedup 1.0000x reference)
//
#include <hip/hip_runtime.h>

// GraphSAGE 2-layer: N=100k nodes, E=800k edges, 128->128(relu)->64.
// Strategy: build CSR once (reused by both layers), atomic-free gather
// aggregation, fp32 vector GEMM with LDS-staged input rows.

#define CH 128  // feature channels for both GEMM inputs (IN_C == HID_C == 128)

// ---------------- CSR build ----------------

__global__ __launch_bounds__(256) void k_zero(int* __restrict__ cnt, int* __restrict__ counter, int N) {
    int i = blockIdx.x * blockDim.x + threadIdx.x;
    if (i < N) cnt[i] = 0;
    if (i == 0) *counter = 0;
}

__global__ __launch_bounds__(256) void k_count(const int* __restrict__ dst, int E, int* __restrict__ cnt) {
    int stride = gridDim.x * blockDim.x;
    for (int e = blockIdx.x * blockDim.x + threadIdx.x; e < E; e += stride)
        atomicAdd(&cnt[dst[e]], 1);
}

// Each node gets a contiguous segment [start, start+deg) in eidx; segment order
// across nodes is arbitrary (one atomicAdd per wave on a global counter).
__global__ __launch_bounds__(256) void k_alloc(const int* __restrict__ cnt, int* __restrict__ start,
                                               int* __restrict__ cursor, int* __restrict__ counter, int N) {
    int n = blockIdx.x * blockDim.x + threadIdx.x;
    int lane = threadIdx.x & 63;
    int d = (n < N) ? cnt[n] : 0;
    int x = d;
#pragma unroll
    for (int o = 1; o < 64; o <<= 1) {
        int y = __shfl_up(x, o);
        if (lane >= o) x += y;
    }
    int total = __shfl(x, 63);   // wave's inclusive total
    int base = 0;
    if (lane == 63) base = atomicAdd(counter, total);
    base = __shfl(base, 63);
    int st = base + x - d;       // exclusive prefix within wave + wave base
    if (n < N) { start[n] = st; cursor[n] = st; }
}

__global__ __launch_bounds__(256) void k_fill(const int* __restrict__ src, const int* __restrict__ dst, int E,
                                              int* __restrict__ cursor, int* __restrict__ eidx) {
    int stride = gridDim.x * blockDim.x;
    for (int e = blockIdx.x * blockDim.x + threadIdx.x; e += stride, true;) {
        // rewritten below to avoid odd loop form
        break;
    }
    for (int e = blockIdx.x * blockDim.x + threadIdx.x; e < E; e += stride) {
        int p = atomicAdd(&cursor[dst[e]], 1);
        eidx[p] = src[e];
    }
}

// ---------------- mean aggregation (atomic-free gather) ----------------
// 32 threads per node, float4 per thread covers 128 channels.
__global__ __launch_bounds__(256) void k_agg_mean(const float* __restrict__ feat, const int* __restrict__ start,
                                                  const int* __restrict__ cnt, const int* __restrict__ eidx,
                                                  float* __restrict__ agg, int N) {
    int g = threadIdx.x >> 5;          // node group within block (8 per block)
    int l = threadIdx.x & 31;          // lane within group
    int n = blockIdx.x * 8 + g;
    if (n >= N) return;
    int s0 = start[n];
    int d  = cnt[n];
    float ax = 0.f, ay = 0.f, az = 0.f, aw = 0.f;
    for (int i = 0; i < d; ++i) {
        int s = eidx[s0 + i];
        const float4 v = *(const float4*)&feat[(size_t)s * CH + (l << 2)];
        ax += v.x; ay += v.y; az += v.z; aw += v.w;
    }
    float sc = 1.0f / (float)(d > 0 ? d : 1);
    float4 o; o.x = ax * sc; o.y = ay * sc; o.z = az * sc; o.w = aw * sc;
    *(float4*)&agg[(size_t)n * CH + (l << 2)] = o;
}

// ---------------- fused dual-GEMM: out = A1@Wl + A2@Wr + b (opt. ReLU) ----------------
// Block stages NPB node rows ([A1 row | A2 row] = 256 floats) into LDS with a
// padded stride (260) so the 8/16 node-groups' k-broadcast reads hit distinct banks.
template <int COUT, bool RELU>
__global__ __launch_bounds__(256) void k_sage_gemm(const float* __restrict__ A1, const float* __restrict__ A2,
                                                   const float* __restrict__ Wl, const float* __restrict__ Wr,
                                                   const float* __restrict__ bias, float* __restrict__ out, int N) {
    constexpr int CG  = COUT / 4;      // column groups (float4 wide)
    constexpr int NPB = 256 / CG;      // node rows per block (8 for COUT=128, 16 for COUT=64)
    constexpr int STRIDE = 2 * CH + 4; // 260 floats: +4 pad shifts banks per row
    __shared__ float lds[NPB * STRIDE];

    int n0 = blockIdx.x * NPB;

    // stage [A1 | A2] rows, float4-granular, coalesced
    for (int f = threadIdx.x; f < NPB * 64; f += 256) {
        int nl = f >> 6;               // local node
        int q  = f & 63;               // float4 slot within 256-float row
        int n  = n0 + nl;
        float4 v;
        if (n < N) {
            if (q < 32) v = *(const float4*)&A1[(size_t)n * CH + (q << 2)];
            else        v = *(const float4*)&A2[(size_t)n * CH + ((q - 32) << 2)];
        } else {
            v.x = v.y = v.z = v.w = 0.f;
        }
        *(float4*)&lds[nl * STRIDE + (q << 2)] = v;
    }
    __syncthreads();

    int cg = threadIdx.x % CG;
    int nl = threadIdx.x / CG;
    int n  = n0 + nl;
    int c4 = cg << 2;

    float4 acc = *(const float4*)&bias[c4];
    const float* in1 = &lds[nl * STRIDE];
    const float* in2 = in1 + CH;

#pragma unroll 8
    for (int k = 0; k < CH; ++k) {
        float a = in1[k];
        const float4 w = *(const float4*)&Wl[k * COUT + c4];
        acc.x = fmaf(a, w.x, acc.x); acc.y = fmaf(a, w.y, acc.y);
        acc.z = fmaf(a, w.z, acc.z); acc.w = fmaf(a, w.w, acc.w);
    }
#pragma unroll 8
    for (int k = 0; k < CH; ++k) {
        float a = in2[k];
        const float4 w = *(const float4*)&Wr[k * COUT + c4];
        acc.x = fmaf(a, w.x, acc.x); acc.y = fmaf(a, w.y, acc.y);
        acc.z = fmaf(a, w.z, acc.z); acc.w = fmaf(a, w.w, acc.w);
    }
    if (RELU) {
        acc.x = fmaxf(acc.x, 0.f); acc.y = fmaxf(acc.y, 0.f);
        acc.z = fmaxf(acc.z, 0.f); acc.w = fmaxf(acc.w, 0.f);
    }
    if (n < N) *(float4*)&out[(size_t)n * COUT + c4] = acc;
}

// ---------------- launch ----------------

extern "C" void kernel_launch(void* const* d_in, const int* in_sizes, int n_in,
                              void* d_out, int out_size, void* d_ws, size_t ws_size,
                              hipStream_t stream) {
    const float* x   = (const float*)d_in[0];
    const int*   ei  = (const int*)d_in[1];
    const float* W1l = (const float*)d_in[2];
    const float* W1r = (const float*)d_in[3];
    const float* b1  = (const float*)d_in[4];
    const float* W2l = (const float*)d_in[5];
    const float* W2r = (const float*)d_in[6];
    const float* b2  = (const float*)d_in[7];
    float* out = (float*)d_out;

    const int N = in_sizes[0] / CH;
    const int E = in_sizes[1] / 2;
    const int* src = ei;
    const int* dst = ei + E;

    // workspace carve (all 16B-aligned given N,E multiples of 8)
    char* w = (char*)d_ws;
    size_t o = 0;
    int* cnt     = (int*)(w + o); o += (size_t)N * 4;
    int* start   = (int*)(w + o); o += (size_t)N * 4;
    int* cursor  = (int*)(w + o); o += (size_t)N * 4;
    int* counter = (int*)(w + o); o += 16;
    int* eidx    = (int*)(w + o); o += (size_t)E * 4;
    float* agg   = (float*)(w + o); o += (size_t)N * CH * 4;
    float* h     = (float*)(w + o); o += (size_t)N * CH * 4;
    (void)ws_size; (void)n_in; (void)out_size;

    const int TB = 256;
    int zb = (N + TB - 1) / TB;

    hipLaunchKernelGGL(k_zero, dim3(zb), dim3(TB), 0, stream, cnt, counter, N);
    hipLaunchKernelGGL(k_count, dim3(1024), dim3(TB), 0, stream, dst, E, cnt);
    hipLaunchKernelGGL(k_alloc, dim3(zb), dim3(TB), 0, stream, cnt, start, cursor, counter, N);
    hipLaunchKernelGGL(k_fill, dim3(1024), dim3(TB), 0, stream, src, dst, E, cursor, eidx);

    int ab = (N + 7) / 8;
    // layer 1
    hipLaunchKernelGGL(k_agg_mean, dim3(ab), dim3(TB), 0, stream, x, start, cnt, eidx, agg, N);
    hipLaunchKernelGGL((k_sage_gemm<128, true>), dim3((N + 7) / 8), dim3(TB), 0, stream,
                       agg, x, W1l, W1r, b1, h, N);
    // layer 2
    hipLaunchKernelGGL(k_agg_mean, dim3(ab), dim3(TB), 0, stream, h, start, cnt, eidx, agg, N);
    hipLaunchKernelGGL((k_sage_gemm<64, false>), dim3((N + 15) / 16), dim3(TB), 0, stream,
                       agg, h, W2l, W2r, b2, out, N);
}

// Round 2
// 510.710 us; speedup vs baseline: 1.7346x; 1.7346x over previous
//
#include <hip/hip_runtime.h>

// GraphSAGE 2-layer: N=100k nodes, E=800k edges, 128->128(relu)->64.
// R1: register-blocked fp32 GEMM (each W load amortized over R rows) to kill
// the L2-BW-bound W re-fetch (was 31.8 TB/s sustained = L2 ceiling).

#define CH 128  // feature channels for both GEMM inputs (IN_C == HID_C == 128)

// ---------------- CSR build ----------------

__global__ __launch_bounds__(256) void k_zero(int* __restrict__ cnt, int* __restrict__ counter, int N) {
    int i = blockIdx.x * blockDim.x + threadIdx.x;
    if (i < N) cnt[i] = 0;
    if (i == 0) *counter = 0;
}

__global__ __launch_bounds__(256) void k_count(const int* __restrict__ dst, int E, int* __restrict__ cnt) {
    int stride = gridDim.x * blockDim.x;
    for (int e = blockIdx.x * blockDim.x + threadIdx.x; e < E; e += stride)
        atomicAdd(&cnt[dst[e]], 1);
}

// Each node gets a contiguous segment [start, start+deg) in eidx; segment order
// across nodes is arbitrary (one atomicAdd per wave on a global counter).
__global__ __launch_bounds__(256) void k_alloc(const int* __restrict__ cnt, int* __restrict__ start,
                                               int* __restrict__ cursor, int* __restrict__ counter, int N) {
    int n = blockIdx.x * blockDim.x + threadIdx.x;
    int lane = threadIdx.x & 63;
    int d = (n < N) ? cnt[n] : 0;
    int x = d;
#pragma unroll
    for (int o = 1; o < 64; o <<= 1) {
        int y = __shfl_up(x, o);
        if (lane >= o) x += y;
    }
    int total = __shfl(x, 63);   // wave's inclusive total
    int base = 0;
    if (lane == 63) base = atomicAdd(counter, total);
    base = __shfl(base, 63);
    int st = base + x - d;       // exclusive prefix within wave + wave base
    if (n < N) { start[n] = st; cursor[n] = st; }
}

__global__ __launch_bounds__(256) void k_fill(const int* __restrict__ src, const int* __restrict__ dst, int E,
                                              int* __restrict__ cursor, int* __restrict__ eidx) {
    int stride = gridDim.x * blockDim.x;
    for (int e = blockIdx.x * blockDim.x + threadIdx.x; e < E; e += stride) {
        int p = atomicAdd(&cursor[dst[e]], 1);
        eidx[p] = src[e];
    }
}

// ---------------- mean aggregation (atomic-free gather) ----------------
// 32 threads per node, float4 per thread covers 128 channels.
__global__ __launch_bounds__(256) void k_agg_mean(const float* __restrict__ feat, const int* __restrict__ start,
                                                  const int* __restrict__ cnt, const int* __restrict__ eidx,
                                                  float* __restrict__ agg, int N) {
    int g = threadIdx.x >> 5;          // node group within block (8 per block)
    int l = threadIdx.x & 31;          // lane within group
    int n = blockIdx.x * 8 + g;
    if (n >= N) return;
    int s0 = start[n];
    int d  = cnt[n];
    float ax = 0.f, ay = 0.f, az = 0.f, aw = 0.f;
    for (int i = 0; i < d; ++i) {
        int s = eidx[s0 + i];
        const float4 v = *(const float4*)&feat[(size_t)s * CH + (l << 2)];
        ax += v.x; ay += v.y; az += v.z; aw += v.w;
    }
    float sc = 1.0f / (float)(d > 0 ? d : 1);
    float4 o; o.x = ax * sc; o.y = ay * sc; o.z = az * sc; o.w = aw * sc;
    *(float4*)&agg[(size_t)n * CH + (l << 2)] = o;
}

// ---------------- fused dual-GEMM: out = A1@Wl + A2@Wr + b (opt. ReLU) ----------------
// Register-blocked: 64 node rows per block; thread owns R rows x 4 cols, so each
// W float4 load is amortized over R rows (W L2 traffic /R). Input rows staged in
// LDS one operand at a time (64 x 132 floats = 33 KB -> 4 blocks/CU).
template <int COUT, bool RELU>
__global__ __launch_bounds__(256) void k_sage_gemm(const float* __restrict__ A1, const float* __restrict__ A2,
                                                   const float* __restrict__ Wl, const float* __restrict__ Wr,
                                                   const float* __restrict__ bias, float* __restrict__ out, int N) {
    constexpr int CG   = COUT / 4;   // column groups (float4 wide): 32 / 16
    constexpr int RG   = 256 / CG;   // thread rows: 8 / 16
    constexpr int ROWS = 64;         // node rows per block
    constexpr int R    = ROWS / RG;  // rows per thread: 8 / 4
    constexpr int STRIDE = CH + 4;   // 132 floats, 16B-aligned rows
    __shared__ float lds[ROWS * STRIDE];

    const int n0 = blockIdx.x * ROWS;
    const int cg = threadIdx.x % CG;
    const int nl = threadIdx.x / CG;
    const int c4 = cg << 2;
    const int r0 = nl * R;

    float4 acc[R];
    {
        const float4 bv = *(const float4*)&bias[c4];
#pragma unroll
        for (int r = 0; r < R; ++r) acc[r] = bv;
    }

#pragma unroll 1
    for (int pass = 0; pass < 2; ++pass) {
        const float* __restrict__ A = pass ? A2 : A1;
        const float* __restrict__ W = pass ? Wr : Wl;

        if (pass) __syncthreads();   // previous compute done before restaging
        // stage 64 rows x 128 floats, coalesced float4
        for (int f = threadIdx.x; f < ROWS * 32; f += 256) {
            int rl = f >> 5;
            int q  = f & 31;
            int n  = n0 + rl;
            float4 v = make_float4(0.f, 0.f, 0.f, 0.f);
            if (n < N) v = *(const float4*)&A[(size_t)n * CH + (q << 2)];
            *(float4*)&lds[rl * STRIDE + (q << 2)] = v;
        }
        __syncthreads();

        const float* __restrict__ wp = W + c4;
#pragma unroll 2
        for (int k = 0; k < CH; k += 4) {
            const float4 w0 = *(const float4*)&wp[(k + 0) * COUT];
            const float4 w1 = *(const float4*)&wp[(k + 1) * COUT];
            const float4 w2 = *(const float4*)&wp[(k + 2) * COUT];
            const float4 w3 = *(const float4*)&wp[(k + 3) * COUT];
#pragma unroll
            for (int r = 0; r < R; ++r) {
                const float4 a = *(const float4*)&lds[(r0 + r) * STRIDE + k];
                acc[r].x = fmaf(a.x, w0.x, acc[r].x);
                acc[r].y = fmaf(a.x, w0.y, acc[r].y);
                acc[r].z = fmaf(a.x, w0.z, acc[r].z);
                acc[r].w = fmaf(a.x, w0.w, acc[r].w);
                acc[r].x = fmaf(a.y, w1.x, acc[r].x);
                acc[r].y = fmaf(a.y, w1.y, acc[r].y);
                acc[r].z = fmaf(a.y, w1.z, acc[r].z);
                acc[r].w = fmaf(a.y, w1.w, acc[r].w);
                acc[r].x = fmaf(a.z, w2.x, acc[r].x);
                acc[r].y = fmaf(a.z, w2.y, acc[r].y);
                acc[r].z = fmaf(a.z, w2.z, acc[r].z);
                acc[r].w = fmaf(a.z, w2.w, acc[r].w);
                acc[r].x = fmaf(a.w, w3.x, acc[r].x);
                acc[r].y = fmaf(a.w, w3.y, acc[r].y);
                acc[r].z = fmaf(a.w, w3.z, acc[r].z);
                acc[r].w = fmaf(a.w, w3.w, acc[r].w);
            }
        }
    }

#pragma unroll
    for (int r = 0; r < R; ++r) {
        int n = n0 + r0 + r;
        if (n < N) {
            float4 v = acc[r];
            if (RELU) {
                v.x = fmaxf(v.x, 0.f); v.y = fmaxf(v.y, 0.f);
                v.z = fmaxf(v.z, 0.f); v.w = fmaxf(v.w, 0.f);
            }
            *(float4*)&out[(size_t)n * COUT + c4] = v;
        }
    }
}

// ---------------- launch ----------------

extern "C" void kernel_launch(void* const* d_in, const int* in_sizes, int n_in,
                              void* d_out, int out_size, void* d_ws, size_t ws_size,
                              hipStream_t stream) {
    const float* x   = (const float*)d_in[0];
    const int*   ei  = (const int*)d_in[1];
    const float* W1l = (const float*)d_in[2];
    const float* W1r = (const float*)d_in[3];
    const float* b1  = (const float*)d_in[4];
    const float* W2l = (const float*)d_in[5];
    const float* W2r = (const float*)d_in[6];
    const float* b2  = (const float*)d_in[7];
    float* out = (float*)d_out;

    const int N = in_sizes[0] / CH;
    const int E = in_sizes[1] / 2;
    const int* src = ei;
    const int* dst = ei + E;

    // workspace carve (all 16B-aligned given N,E multiples of 8)
    char* w = (char*)d_ws;
    size_t o = 0;
    int* cnt     = (int*)(w + o); o += (size_t)N * 4;
    int* start   = (int*)(w + o); o += (size_t)N * 4;
    int* cursor  = (int*)(w + o); o += (size_t)N * 4;
    int* counter = (int*)(w + o); o += 16;
    int* eidx    = (int*)(w + o); o += (size_t)E * 4;
    float* agg   = (float*)(w + o); o += (size_t)N * CH * 4;
    float* h     = (float*)(w + o); o += (size_t)N * CH * 4;
    (void)ws_size; (void)n_in; (void)out_size;

    const int TB = 256;
    int zb = (N + TB - 1) / TB;

    hipLaunchKernelGGL(k_zero, dim3(zb), dim3(TB), 0, stream, cnt, counter, N);
    hipLaunchKernelGGL(k_count, dim3(1024), dim3(TB), 0, stream, dst, E, cnt);
    hipLaunchKernelGGL(k_alloc, dim3(zb), dim3(TB), 0, stream, cnt, start, cursor, counter, N);
    hipLaunchKernelGGL(k_fill, dim3(1024), dim3(TB), 0, stream, src, dst, E, cursor, eidx);

    int ab = (N + 7) / 8;
    int gb = (N + 63) / 64;
    // layer 1
    hipLaunchKernelGGL(k_agg_mean, dim3(ab), dim3(TB), 0, stream, x, start, cnt, eidx, agg, N);
    hipLaunchKernelGGL((k_sage_gemm<128, true>), dim3(gb), dim3(TB), 0, stream,
                       agg, x, W1l, W1r, b1, h, N);
    // layer 2
    hipLaunchKernelGGL(k_agg_mean, dim3(ab), dim3(TB), 0, stream, h, start, cnt, eidx, agg, N);
    hipLaunchKernelGGL((k_sage_gemm<64, false>), dim3(gb), dim3(TB), 0, stream,
                       agg, h, W2l, W2r, b2, out, N);
}

// Round 3
// 473.663 us; speedup vs baseline: 1.8703x; 1.0782x over previous
//
#include <hip/hip_runtime.h>

// GraphSAGE 2-layer: N=100k, E=800k, 128->128(relu)->64.
// R2: transform-first (mean(x)@W == mean(x@W)) + dual-output GEMM.
//   gemm1: g1 = x@W1l, p1 = x@W1r + b1          (x staged once)
//   agg1 : h  = relu(mean_agg(g1) + p1)         (gather 128ch, h aliases p1)
//   gemm2: g2 = h@W2l, p2 = h@W2r + b2          (h staged once)
//   agg2 : out = mean_agg(g2) + p2              (gather 64ch only)
// Gather loop unrolled x4 for memory-level parallelism.

#define CH 128  // input channels of both GEMMs (IN_C == HID_C == 128)

// ---------------- CSR build ----------------

__global__ __launch_bounds__(256) void k_zero(int* __restrict__ cnt, int* __restrict__ counter, int N) {
    int i = blockIdx.x * blockDim.x + threadIdx.x;
    if (i < N) cnt[i] = 0;
    if (i == 0) *counter = 0;
}

__global__ __launch_bounds__(256) void k_count(const int* __restrict__ dst, int E, int* __restrict__ cnt) {
    int stride = gridDim.x * blockDim.x;
    for (int e = blockIdx.x * blockDim.x + threadIdx.x; e < E; e += stride)
        atomicAdd(&cnt[dst[e]], 1);
}

// Contiguous per-node segments; one global atomic per wave (wave prefix scan).
__global__ __launch_bounds__(256) void k_alloc(const int* __restrict__ cnt, int* __restrict__ start,
                                               int* __restrict__ cursor, int* __restrict__ counter, int N) {
    int n = blockIdx.x * blockDim.x + threadIdx.x;
    int lane = threadIdx.x & 63;
    int d = (n < N) ? cnt[n] : 0;
    int x = d;
#pragma unroll
    for (int o = 1; o < 64; o <<= 1) {
        int y = __shfl_up(x, o);
        if (lane >= o) x += y;
    }
    int total = __shfl(x, 63);
    int base = 0;
    if (lane == 63) base = atomicAdd(counter, total);
    base = __shfl(base, 63);
    int st = base + x - d;
    if (n < N) { start[n] = st; cursor[n] = st; }
}

__global__ __launch_bounds__(256) void k_fill(const int* __restrict__ src, const int* __restrict__ dst, int E,
                                              int* __restrict__ cursor, int* __restrict__ eidx) {
    int stride = gridDim.x * blockDim.x;
    for (int e = blockIdx.x * blockDim.x + threadIdx.x; e < E; e += stride) {
        int p = atomicAdd(&cursor[dst[e]], 1);
        eidx[p] = src[e];
    }
}

// ---------------- dual-output GEMM: Ga = X@Wa, Pb = X@Wb + bias ----------------
// 64 rows/block staged once in LDS; thread owns R rows x 4 cols of ONE output.
// C2=128: 64 col-groups, R=16 (wave = single row-set -> LDS reads broadcast).
// C2=64 : 32 col-groups, R=8.
__device__ __forceinline__ void fma4(float4& c, float a, const float4& w) {
    c.x = fmaf(a, w.x, c.x); c.y = fmaf(a, w.y, c.y);
    c.z = fmaf(a, w.z, c.z); c.w = fmaf(a, w.w, c.w);
}

template <int C2>
__global__ __launch_bounds__(256) void k_gemm_dual(const float* __restrict__ X,
                                                   const float* __restrict__ Wa,
                                                   const float* __restrict__ Wb,
                                                   const float* __restrict__ bias,
                                                   float* __restrict__ Ga,
                                                   float* __restrict__ Pb, int N) {
    constexpr int CGT  = 2 * C2 / 4;   // total float4 col-groups across both outputs
    constexpr int RG   = 256 / CGT;    // thread-row sets
    constexpr int ROWS = 64;
    constexpr int R    = ROWS / RG;    // rows per thread: 16 / 8
    __shared__ float lds[ROWS * CH];   // 32 KB

    const int n0 = blockIdx.x * ROWS;
    const int cg = threadIdx.x % CGT;
    const int nl = threadIdx.x / CGT;
    const int r0 = nl * R;
    const bool isB = (cg >= C2 / 4);
    const int c4 = (isB ? cg - C2 / 4 : cg) << 2;
    const float* __restrict__ Wp = (isB ? Wb : Wa) + c4;

    // stage X rows (coalesced float4)
    for (int f = threadIdx.x; f < ROWS * (CH / 4); f += 256) {
        int rl = f >> 5;               // CH/4 == 32
        int q  = f & 31;
        int n  = n0 + rl;
        float4 v = make_float4(0.f, 0.f, 0.f, 0.f);
        if (n < N) v = *(const float4*)&X[(size_t)n * CH + (q << 2)];
        *(float4*)&lds[rl * CH + (q << 2)] = v;
    }
    __syncthreads();

    float4 acc[R];
    {
        float4 bv = make_float4(0.f, 0.f, 0.f, 0.f);
        if (isB) bv = *(const float4*)&bias[c4];
#pragma unroll
        for (int r = 0; r < R; ++r) acc[r] = bv;
    }

    // k loop in groups of 4, W prefetched one group ahead (L2-hit latency hiding)
    float4 w0 = *(const float4*)&Wp[0 * C2];
    float4 w1 = *(const float4*)&Wp[1 * C2];
    float4 w2 = *(const float4*)&Wp[2 * C2];
    float4 w3 = *(const float4*)&Wp[3 * C2];
#pragma unroll 1
    for (int kg = 0; kg < CH / 4; ++kg) {
        const int kn = ((kg + 1) & (CH / 4 - 1)) << 2;  // wraps to 0 on last iter
        const float4 nw0 = *(const float4*)&Wp[(kn + 0) * C2];
        const float4 nw1 = *(const float4*)&Wp[(kn + 1) * C2];
        const float4 nw2 = *(const float4*)&Wp[(kn + 2) * C2];
        const float4 nw3 = *(const float4*)&Wp[(kn + 3) * C2];
        const int kb = kg << 2;
#pragma unroll
        for (int r = 0; r < R; ++r) {
            const float4 a = *(const float4*)&lds[(r0 + r) * CH + kb];
            fma4(acc[r], a.x, w0);
            fma4(acc[r], a.y, w1);
            fma4(acc[r], a.z, w2);
            fma4(acc[r], a.w, w3);
        }
        w0 = nw0; w1 = nw1; w2 = nw2; w3 = nw3;
    }

    float* __restrict__ O = isB ? Pb : Ga;
#pragma unroll
    for (int r = 0; r < R; ++r) {
        int n = n0 + r0 + r;
        if (n < N) *(float4*)&O[(size_t)n * C2 + c4] = acc[r];
    }
}

// ---------------- combined aggregation: out = [relu](mean_gather(G) + P) ----------------
// CHW/4 lanes per node; gather loop unrolled x4 for MLP.
template <int CHW, bool RELU>
__global__ __launch_bounds__(256) void k_agg_comb(const float* __restrict__ G,
                                                  const float* __restrict__ P,
                                                  const int* __restrict__ start,
                                                  const int* __restrict__ cnt,
                                                  const int* __restrict__ eidx,
                                                  float* __restrict__ outp, int N) {
    constexpr int LPN = CHW / 4;       // lanes per node: 32 / 16
    constexpr int NPB = 256 / LPN;     // nodes per block: 8 / 16
    const int g = threadIdx.x / LPN;
    const int l = threadIdx.x % LPN;
    const int n = blockIdx.x * NPB + g;
    if (n >= N) return;
    const int s0 = start[n];
    const int d  = cnt[n];
    const int* __restrict__ ep = eidx + s0;
    const int co = l << 2;

    float4 a = make_float4(0.f, 0.f, 0.f, 0.f);
    int i = 0;
    for (; i + 4 <= d; i += 4) {
        const int e0 = ep[i], e1 = ep[i + 1], e2 = ep[i + 2], e3 = ep[i + 3];
        const float4 v0 = *(const float4*)&G[(size_t)e0 * CHW + co];
        const float4 v1 = *(const float4*)&G[(size_t)e1 * CHW + co];
        const float4 v2 = *(const float4*)&G[(size_t)e2 * CHW + co];
        const float4 v3 = *(const float4*)&G[(size_t)e3 * CHW + co];
        a.x += (v0.x + v1.x) + (v2.x + v3.x);
        a.y += (v0.y + v1.y) + (v2.y + v3.y);
        a.z += (v0.z + v1.z) + (v2.z + v3.z);
        a.w += (v0.w + v1.w) + (v2.w + v3.w);
    }
    for (; i < d; ++i) {
        const int e = ep[i];
        const float4 v = *(const float4*)&G[(size_t)e * CHW + co];
        a.x += v.x; a.y += v.y; a.z += v.z; a.w += v.w;
    }

    const float sc = 1.0f / (float)(d > 0 ? d : 1);
    const float4 p = *(const float4*)&P[(size_t)n * CHW + co];
    float4 r;
    r.x = fmaf(a.x, sc, p.x);
    r.y = fmaf(a.y, sc, p.y);
    r.z = fmaf(a.z, sc, p.z);
    r.w = fmaf(a.w, sc, p.w);
    if (RELU) {
        r.x = fmaxf(r.x, 0.f); r.y = fmaxf(r.y, 0.f);
        r.z = fmaxf(r.z, 0.f); r.w = fmaxf(r.w, 0.f);
    }
    *(float4*)&outp[(size_t)n * CHW + co] = r;
}

// ---------------- launch ----------------

extern "C" void kernel_launch(void* const* d_in, const int* in_sizes, int n_in,
                              void* d_out, int out_size, void* d_ws, size_t ws_size,
                              hipStream_t stream) {
    const float* x   = (const float*)d_in[0];
    const int*   ei  = (const int*)d_in[1];
    const float* W1l = (const float*)d_in[2];
    const float* W1r = (const float*)d_in[3];
    const float* b1  = (const float*)d_in[4];
    const float* W2l = (const float*)d_in[5];
    const float* W2r = (const float*)d_in[6];
    const float* b2  = (const float*)d_in[7];
    float* out = (float*)d_out;

    const int N = in_sizes[0] / CH;
    const int E = in_sizes[1] / 2;
    const int* src = ei;
    const int* dst = ei + E;

    // workspace carve
    char* w = (char*)d_ws;
    size_t o = 0;
    int* cnt     = (int*)(w + o); o += (size_t)N * 4;
    int* start   = (int*)(w + o); o += (size_t)N * 4;
    int* cursor  = (int*)(w + o); o += (size_t)N * 4;
    int* counter = (int*)(w + o); o += 16;
    int* eidx    = (int*)(w + o); o += (size_t)E * 4;
    float* bufA  = (float*)(w + o); o += (size_t)N * CH * 4;  // g1, later {g2,p2}
    float* bufB  = (float*)(w + o); o += (size_t)N * CH * 4;  // p1 / h (aliased)
    (void)ws_size; (void)n_in; (void)out_size;

    float* g1 = bufA;
    float* p1 = bufB;          // h written in place over p1 (same-element RMW)
    float* h  = bufB;
    float* g2 = bufA;          // g1 dead after agg1
    float* p2 = bufA + (size_t)N * 64;

    const int TB = 256;
    const int zb = (N + TB - 1) / TB;
    const int gb = (N + 63) / 64;

    hipLaunchKernelGGL(k_zero,  dim3(zb),   dim3(TB), 0, stream, cnt, counter, N);
    hipLaunchKernelGGL(k_count, dim3(2048), dim3(TB), 0, stream, dst, E, cnt);
    hipLaunchKernelGGL(k_alloc, dim3(zb),   dim3(TB), 0, stream, cnt, start, cursor, counter, N);
    hipLaunchKernelGGL(k_fill,  dim3(2048), dim3(TB), 0, stream, src, dst, E, cursor, eidx);

    // layer 1: g1 = x@W1l, p1 = x@W1r + b1 ; h = relu(mean(g1) + p1)
    hipLaunchKernelGGL((k_gemm_dual<128>), dim3(gb), dim3(TB), 0, stream,
                       x, W1l, W1r, b1, g1, p1, N);
    hipLaunchKernelGGL((k_agg_comb<128, true>), dim3((N + 7) / 8), dim3(TB), 0, stream,
                       g1, p1, start, cnt, eidx, h, N);
    // layer 2: g2 = h@W2l, p2 = h@W2r + b2 ; out = mean(g2) + p2
    hipLaunchKernelGGL((k_gemm_dual<64>), dim3(gb), dim3(TB), 0, stream,
                       h, W2l, W2r, b2, g2, p2, N);
    hipLaunchKernelGGL((k_agg_comb<64, false>), dim3((N + 15) / 16), dim3(TB), 0, stream,
                       g2, p2, start, cnt, eidx, out, N);
}

// Round 4
// 417.508 us; speedup vs baseline: 2.1218x; 1.1345x over previous
//
#include <hip/hip_runtime.h>

// GraphSAGE 2-layer: N=100k, E=800k, 128->128(relu)->64. fp32 in/out.
// R3: GEMMs moved to MFMA with split-bf16 (hi+lo) operands for fp32-grade
// accuracy: C = Ahi@Bhi + Alo@Bhi + Ahi@Blo, fp32 accumulate.
// W pre-packed per call into B-fragment order (hi/lo bf16, L2-resident).
// Transform-first structure unchanged:
//   gemm1: g1 = x@W1l, p1 = x@W1r + b1 ; agg1: h = relu(mean(g1)+p1)
//   gemm2: g2 = h@W2l, p2 = h@W2r + b2 ; agg2: out = mean(g2)+p2

#define CH 128

typedef short short8 __attribute__((ext_vector_type(8)));
typedef float f32x4 __attribute__((ext_vector_type(4)));

__device__ __forceinline__ short f2bf(float x) {        // RNE fp32->bf16
    unsigned u = __float_as_uint(x);
    unsigned r = u + 0x7FFFu + ((u >> 16) & 1u);
    return (short)(r >> 16);
}
__device__ __forceinline__ float b2f(short s) {
    return __uint_as_float(((unsigned)(unsigned short)s) << 16);
}

// ---------------- CSR build ----------------

__global__ __launch_bounds__(256) void k_zero(int* __restrict__ cnt, int* __restrict__ counter, int N) {
    int i = blockIdx.x * blockDim.x + threadIdx.x;
    if (i < N) cnt[i] = 0;
    if (i == 0) *counter = 0;
}

__global__ __launch_bounds__(256) void k_count(const int* __restrict__ dst, int E, int* __restrict__ cnt) {
    int stride = gridDim.x * blockDim.x;
    for (int e = blockIdx.x * blockDim.x + threadIdx.x; e < E; e += stride)
        atomicAdd(&cnt[dst[e]], 1);
}

__global__ __launch_bounds__(256) void k_alloc(const int* __restrict__ cnt, int* __restrict__ start,
                                               int* __restrict__ cursor, int* __restrict__ counter, int N) {
    int n = blockIdx.x * blockDim.x + threadIdx.x;
    int lane = threadIdx.x & 63;
    int d = (n < N) ? cnt[n] : 0;
    int x = d;
#pragma unroll
    for (int o = 1; o < 64; o <<= 1) {
        int y = __shfl_up(x, o);
        if (lane >= o) x += y;
    }
    int total = __shfl(x, 63);
    int base = 0;
    if (lane == 63) base = atomicAdd(counter, total);
    base = __shfl(base, 63);
    int st = base + x - d;
    if (n < N) { start[n] = st; cursor[n] = st; }
}

__global__ __launch_bounds__(256) void k_fill(const int* __restrict__ src, const int* __restrict__ dst, int E,
                                              int* __restrict__ cursor, int* __restrict__ eidx) {
    int stride = gridDim.x * blockDim.x;
    for (int e = blockIdx.x * blockDim.x + threadIdx.x; e < E; e += stride) {
        int p = atomicAdd(&cursor[dst[e]], 1);
        eidx[p] = src[e];
    }
}

// ---------------- W pre-pack into B-fragment order ----------------
// Layout: idx = ((ct*4 + kt)*64 + lane)*8 + j ; c = ct*16 + (lane&15),
// k = kt*32 + (lane>>4)*8 + j. Columns = [Wa | Wb] concatenated (C2 each).
__global__ __launch_bounds__(256) void k_pack(const float* __restrict__ Wa, const float* __restrict__ Wb,
                                              int C2, short* __restrict__ hi, short* __restrict__ lo) {
    int idx = blockIdx.x * 256 + threadIdx.x;
    int tot = 128 * 2 * C2;
    if (idx >= tot) return;
    int j    = idx & 7;
    int lane = (idx >> 3) & 63;
    int kt   = (idx >> 9) & 3;
    int ct   = idx >> 11;
    int c = ct * 16 + (lane & 15);
    int k = kt * 32 + (lane >> 4) * 8 + j;
    float w = (c < C2) ? Wa[k * C2 + c] : Wb[k * C2 + (c - C2)];
    short h = f2bf(w);
    hi[idx] = h;
    lo[idx] = f2bf(w - b2f(h));
}

// ---------------- split-bf16 MFMA dual GEMM ----------------
// Block = 4 waves x 16 rows = 64 rows. Wave computes its 16 rows x all
// (COLS_A+COLS_B) cols: CT col-tiles x 4 k-tiles x 3 mfma (hi*hi, lo*hi, hi*lo).
template <int COLS_A, int COLS_B>
__global__ __launch_bounds__(256) void k_gemm_mfma(const float* __restrict__ X,
                                                   const short* __restrict__ pHi,
                                                   const short* __restrict__ pLo,
                                                   const float* __restrict__ bias,
                                                   float* __restrict__ Ga,
                                                   float* __restrict__ Pb, int N) {
    constexpr int CT = (COLS_A + COLS_B) / 16;
    const int lane = threadIdx.x & 63;
    const int wv   = threadIdx.x >> 6;
    const int n0   = blockIdx.x * 64 + wv * 16;

    // A tile: rows n0..n0+15 x K=128, hi/lo bf16 in-register.
    // A-frag: lane holds A[lane&15][(lane>>4)*8 + j], j=0..7, per 32-k tile.
    short8 Ahi[4], Alo[4];
    {
        int arow = n0 + (lane & 15);
        if (arow >= N) arow = N - 1;                    // clamped load, store predicated
        const float* __restrict__ xr = X + (size_t)arow * CH + (lane >> 4) * 8;
#pragma unroll
        for (int kt = 0; kt < 4; ++kt) {
            const float4 a0 = *(const float4*)(xr + kt * 32);
            const float4 a1 = *(const float4*)(xr + kt * 32 + 4);
            const float av[8] = {a0.x, a0.y, a0.z, a0.w, a1.x, a1.y, a1.z, a1.w};
#pragma unroll
            for (int j = 0; j < 8; ++j) {
                const short h = f2bf(av[j]);
                Ahi[kt][j] = h;
                Alo[kt][j] = f2bf(av[j] - b2f(h));
            }
        }
    }

    const int mrow = n0 + (lane >> 4) * 4;   // D rows: (lane>>4)*4 + r
    const int ncol = lane & 15;              // D col within tile

#pragma unroll
    for (int ct = 0; ct < CT; ++ct) {
        f32x4 acc;
        if (ct * 16 >= COLS_A) {
            const float bv = bias[ct * 16 - COLS_A + ncol];
            acc[0] = bv; acc[1] = bv; acc[2] = bv; acc[3] = bv;
        } else {
            acc[0] = 0.f; acc[1] = 0.f; acc[2] = 0.f; acc[3] = 0.f;
        }
#pragma unroll
        for (int kt = 0; kt < 4; ++kt) {
            const size_t fo = ((size_t)(ct * 4 + kt) * 64 + lane) * 8;
            const short8 bh = *(const short8*)(pHi + fo);
            const short8 bl = *(const short8*)(pLo + fo);
            acc = __builtin_amdgcn_mfma_f32_16x16x32_bf16(Ahi[kt], bh, acc, 0, 0, 0);
            acc = __builtin_amdgcn_mfma_f32_16x16x32_bf16(Alo[kt], bh, acc, 0, 0, 0);
            acc = __builtin_amdgcn_mfma_f32_16x16x32_bf16(Ahi[kt], bl, acc, 0, 0, 0);
        }
        float* __restrict__ O;
        int cw, col = ct * 16 + ncol;
        if (col < COLS_A) { O = Ga; cw = COLS_A; }
        else              { O = Pb; cw = COLS_B; col -= COLS_A; }
#pragma unroll
        for (int r = 0; r < 4; ++r) {
            const int n = mrow + r;
            if (n < N) O[(size_t)n * cw + col] = acc[r];
        }
    }
}

// ---------------- combined aggregation: out = [relu](mean_gather(G) + P) ----------------
template <int CHW, bool RELU>
__global__ __launch_bounds__(256) void k_agg_comb(const float* __restrict__ G,
                                                  const float* __restrict__ P,
                                                  const int* __restrict__ start,
                                                  const int* __restrict__ cnt,
                                                  const int* __restrict__ eidx,
                                                  float* __restrict__ outp, int N) {
    constexpr int LPN = CHW / 4;       // lanes per node: 32 / 16
    constexpr int NPB = 256 / LPN;     // nodes per block: 8 / 16
    const int g = threadIdx.x / LPN;
    const int l = threadIdx.x % LPN;
    const int n = blockIdx.x * NPB + g;
    if (n >= N) return;
    const int s0 = start[n];
    const int d  = cnt[n];
    const int* __restrict__ ep = eidx + s0;
    const int co = l << 2;

    float4 a = make_float4(0.f, 0.f, 0.f, 0.f);
    int i = 0;
    for (; i + 4 <= d; i += 4) {
        const int e0 = ep[i], e1 = ep[i + 1], e2 = ep[i + 2], e3 = ep[i + 3];
        const float4 v0 = *(const float4*)&G[(size_t)e0 * CHW + co];
        const float4 v1 = *(const float4*)&G[(size_t)e1 * CHW + co];
        const float4 v2 = *(const float4*)&G[(size_t)e2 * CHW + co];
        const float4 v3 = *(const float4*)&G[(size_t)e3 * CHW + co];
        a.x += (v0.x + v1.x) + (v2.x + v3.x);
        a.y += (v0.y + v1.y) + (v2.y + v3.y);
        a.z += (v0.z + v1.z) + (v2.z + v3.z);
        a.w += (v0.w + v1.w) + (v2.w + v3.w);
    }
    for (; i < d; ++i) {
        const int e = ep[i];
        const float4 v = *(const float4*)&G[(size_t)e * CHW + co];
        a.x += v.x; a.y += v.y; a.z += v.z; a.w += v.w;
    }

    const float sc = 1.0f / (float)(d > 0 ? d : 1);
    const float4 p = *(const float4*)&P[(size_t)n * CHW + co];
    float4 r;
    r.x = fmaf(a.x, sc, p.x);
    r.y = fmaf(a.y, sc, p.y);
    r.z = fmaf(a.z, sc, p.z);
    r.w = fmaf(a.w, sc, p.w);
    if (RELU) {
        r.x = fmaxf(r.x, 0.f); r.y = fmaxf(r.y, 0.f);
        r.z = fmaxf(r.z, 0.f); r.w = fmaxf(r.w, 0.f);
    }
    *(float4*)&outp[(size_t)n * CHW + co] = r;
}

// ---------------- launch ----------------

extern "C" void kernel_launch(void* const* d_in, const int* in_sizes, int n_in,
                              void* d_out, int out_size, void* d_ws, size_t ws_size,
                              hipStream_t stream) {
    const float* x   = (const float*)d_in[0];
    const int*   ei  = (const int*)d_in[1];
    const float* W1l = (const float*)d_in[2];
    const float* W1r = (const float*)d_in[3];
    const float* b1  = (const float*)d_in[4];
    const float* W2l = (const float*)d_in[5];
    const float* W2r = (const float*)d_in[6];
    const float* b2  = (const float*)d_in[7];
    float* out = (float*)d_out;

    const int N = in_sizes[0] / CH;
    const int E = in_sizes[1] / 2;
    const int* src = ei;
    const int* dst = ei + E;

    // workspace carve
    char* w = (char*)d_ws;
    size_t o = 0;
    int* cnt     = (int*)(w + o); o += (size_t)N * 4;
    int* start   = (int*)(w + o); o += (size_t)N * 4;
    int* cursor  = (int*)(w + o); o += (size_t)N * 4;
    int* counter = (int*)(w + o); o += 16;
    int* eidx    = (int*)(w + o); o += (size_t)E * 4;
    short* pw1h  = (short*)(w + o); o += 32768 * 2;   // 128x256 bf16 hi
    short* pw1l  = (short*)(w + o); o += 32768 * 2;
    short* pw2h  = (short*)(w + o); o += 16384 * 2;   // 128x128 bf16 hi
    short* pw2l  = (short*)(w + o); o += 16384 * 2;
    float* bufA  = (float*)(w + o); o += (size_t)N * CH * 4;  // g1, later {g2,p2}
    float* bufB  = (float*)(w + o); o += (size_t)N * CH * 4;  // p1 / h (aliased)
    (void)ws_size; (void)n_in; (void)out_size;

    float* g1 = bufA;
    float* p1 = bufB;          // h written in place over p1 (same-element RMW)
    float* h  = bufB;
    float* g2 = bufA;          // g1 dead after agg1
    float* p2 = bufA + (size_t)N * 64;

    const int TB = 256;
    const int zb = (N + TB - 1) / TB;
    const int gb = (N + 63) / 64;

    // W pre-pack (L2-resident fragment-order hi/lo bf16)
    hipLaunchKernelGGL(k_pack, dim3(128), dim3(TB), 0, stream, W1l, W1r, 128, pw1h, pw1l);
    hipLaunchKernelGGL(k_pack, dim3(64),  dim3(TB), 0, stream, W2l, W2r, 64,  pw2h, pw2l);

    // CSR
    hipLaunchKernelGGL(k_zero,  dim3(zb),   dim3(TB), 0, stream, cnt, counter, N);
    hipLaunchKernelGGL(k_count, dim3(2048), dim3(TB), 0, stream, dst, E, cnt);
    hipLaunchKernelGGL(k_alloc, dim3(zb),   dim3(TB), 0, stream, cnt, start, cursor, counter, N);
    hipLaunchKernelGGL(k_fill,  dim3(2048), dim3(TB), 0, stream, src, dst, E, cursor, eidx);

    // layer 1: g1 = x@W1l, p1 = x@W1r + b1 ; h = relu(mean(g1) + p1)
    hipLaunchKernelGGL((k_gemm_mfma<128, 128>), dim3(gb), dim3(TB), 0, stream,
                       x, pw1h, pw1l, b1, g1, p1, N);
    hipLaunchKernelGGL((k_agg_comb<128, true>), dim3((N + 7) / 8), dim3(TB), 0, stream,
                       g1, p1, start, cnt, eidx, h, N);
    // layer 2: g2 = h@W2l, p2 = h@W2r + b2 ; out = mean(g2) + p2
    hipLaunchKernelGGL((k_gemm_mfma<64, 64>), dim3(gb), dim3(TB), 0, stream,
                       h, pw2h, pw2l, b2, g2, p2, N);
    hipLaunchKernelGGL((k_agg_comb<64, false>), dim3((N + 15) / 16), dim3(TB), 0, stream,
                       g2, p2, start, cnt, eidx, out, N);
}

// Round 5
// 376.258 us; speedup vs baseline: 2.3544x; 1.1096x over previous
//
#include <hip/hip_runtime.h>

// GraphSAGE 2-layer: N=100k, E=800k, 128->128(relu)->64. fp32 in/out.
// R4: gather operands g1/g2 stored as bf16 (halves the random-gather traffic,
// the measured bottleneck at 3.9 TB/s fabric BW). fp32 accumulate + fp32 P.
// Structure:
//   gemm1: g1(bf16) = x@W1l, p1 = x@W1r + b1 ; agg1: h = relu(mean(g1)+p1)
//   gemm2: g2(bf16) = h@W2l, p2 = h@W2r + b2 ; agg2: out = mean(g2)+p2

#define CH 128

typedef short short8 __attribute__((ext_vector_type(8)));
typedef float f32x4 __attribute__((ext_vector_type(4)));

__device__ __forceinline__ short f2bf(float x) {        // RNE fp32->bf16
    unsigned u = __float_as_uint(x);
    unsigned r = u + 0x7FFFu + ((u >> 16) & 1u);
    return (short)(r >> 16);
}
__device__ __forceinline__ float b2f(short s) {
    return __uint_as_float(((unsigned)(unsigned short)s) << 16);
}

// ---------------- CSR build ----------------

__global__ __launch_bounds__(256) void k_zero(int* __restrict__ cnt, int* __restrict__ counter, int N) {
    int i = blockIdx.x * blockDim.x + threadIdx.x;
    if (i < N) cnt[i] = 0;
    if (i == 0) *counter = 0;
}

__global__ __launch_bounds__(256) void k_count(const int* __restrict__ dst, int E, int* __restrict__ cnt) {
    int stride = gridDim.x * blockDim.x;
    for (int e = blockIdx.x * blockDim.x + threadIdx.x; e < E; e += stride)
        atomicAdd(&cnt[dst[e]], 1);
}

__global__ __launch_bounds__(256) void k_alloc(const int* __restrict__ cnt, int* __restrict__ start,
                                               int* __restrict__ cursor, int* __restrict__ counter, int N) {
    int n = blockIdx.x * blockDim.x + threadIdx.x;
    int lane = threadIdx.x & 63;
    int d = (n < N) ? cnt[n] : 0;
    int x = d;
#pragma unroll
    for (int o = 1; o < 64; o <<= 1) {
        int y = __shfl_up(x, o);
        if (lane >= o) x += y;
    }
    int total = __shfl(x, 63);
    int base = 0;
    if (lane == 63) base = atomicAdd(counter, total);
    base = __shfl(base, 63);
    int st = base + x - d;
    if (n < N) { start[n] = st; cursor[n] = st; }
}

__global__ __launch_bounds__(256) void k_fill(const int* __restrict__ src, const int* __restrict__ dst, int E,
                                              int* __restrict__ cursor, int* __restrict__ eidx) {
    int stride = gridDim.x * blockDim.x;
    for (int e = blockIdx.x * blockDim.x + threadIdx.x; e < E; e += stride) {
        int p = atomicAdd(&cursor[dst[e]], 1);
        eidx[p] = src[e];
    }
}

// ---------------- W pre-pack into B-fragment order ----------------
// idx = ((ct*4 + kt)*64 + lane)*8 + j ; c = ct*16 + (lane&15),
// k = kt*32 + (lane>>4)*8 + j. Columns = [Wa | Wb] concatenated (C2 each).
__global__ __launch_bounds__(256) void k_pack(const float* __restrict__ Wa, const float* __restrict__ Wb,
                                              int C2, short* __restrict__ hi, short* __restrict__ lo) {
    int idx = blockIdx.x * 256 + threadIdx.x;
    int tot = 128 * 2 * C2;
    if (idx >= tot) return;
    int j    = idx & 7;
    int lane = (idx >> 3) & 63;
    int kt   = (idx >> 9) & 3;
    int ct   = idx >> 11;
    int c = ct * 16 + (lane & 15);
    int k = kt * 32 + (lane >> 4) * 8 + j;
    float w = (c < C2) ? Wa[k * C2 + c] : Wb[k * C2 + (c - C2)];
    short h = f2bf(w);
    hi[idx] = h;
    lo[idx] = f2bf(w - b2f(h));
}

// ---------------- split-bf16 MFMA dual GEMM ----------------
// Block = 4 waves x 16 rows. Wave: 16 rows x (COLS_A+COLS_B) cols.
// Ga output stored bf16 (gather operand); Pb stored fp32.
template <int COLS_A, int COLS_B>
__global__ __launch_bounds__(256) void k_gemm_mfma(const float* __restrict__ X,
                                                   const short* __restrict__ pHi,
                                                   const short* __restrict__ pLo,
                                                   const float* __restrict__ bias,
                                                   unsigned short* __restrict__ Ga,
                                                   float* __restrict__ Pb, int N) {
    constexpr int CT = (COLS_A + COLS_B) / 16;
    const int lane = threadIdx.x & 63;
    const int wv   = threadIdx.x >> 6;
    const int n0   = blockIdx.x * 64 + wv * 16;

    // A-frag: lane holds A[lane&15][(lane>>4)*8 + j], per 32-k tile; hi/lo split.
    short8 Ahi[4], Alo[4];
    {
        int arow = n0 + (lane & 15);
        if (arow >= N) arow = N - 1;                    // clamped load, store predicated
        const float* __restrict__ xr = X + (size_t)arow * CH + (lane >> 4) * 8;
#pragma unroll
        for (int kt = 0; kt < 4; ++kt) {
            const float4 a0 = *(const float4*)(xr + kt * 32);
            const float4 a1 = *(const float4*)(xr + kt * 32 + 4);
            const float av[8] = {a0.x, a0.y, a0.z, a0.w, a1.x, a1.y, a1.z, a1.w};
#pragma unroll
            for (int j = 0; j < 8; ++j) {
                const short h = f2bf(av[j]);
                Ahi[kt][j] = h;
                Alo[kt][j] = f2bf(av[j] - b2f(h));
            }
        }
    }

    const int mrow = n0 + (lane >> 4) * 4;   // D rows: (lane>>4)*4 + r
    const int ncol = lane & 15;              // D col within tile

#pragma unroll
    for (int ct = 0; ct < CT; ++ct) {
        f32x4 acc;
        if (ct * 16 >= COLS_A) {
            const float bv = bias[ct * 16 - COLS_A + ncol];
            acc[0] = bv; acc[1] = bv; acc[2] = bv; acc[3] = bv;
        } else {
            acc[0] = 0.f; acc[1] = 0.f; acc[2] = 0.f; acc[3] = 0.f;
        }
#pragma unroll
        for (int kt = 0; kt < 4; ++kt) {
            const size_t fo = ((size_t)(ct * 4 + kt) * 64 + lane) * 8;
            const short8 bh = *(const short8*)(pHi + fo);
            const short8 bl = *(const short8*)(pLo + fo);
            acc = __builtin_amdgcn_mfma_f32_16x16x32_bf16(Ahi[kt], bh, acc, 0, 0, 0);
            acc = __builtin_amdgcn_mfma_f32_16x16x32_bf16(Alo[kt], bh, acc, 0, 0, 0);
            acc = __builtin_amdgcn_mfma_f32_16x16x32_bf16(Ahi[kt], bl, acc, 0, 0, 0);
        }
        int col = ct * 16 + ncol;
        if (col < COLS_A) {
#pragma unroll
            for (int r = 0; r < 4; ++r) {
                const int n = mrow + r;
                if (n < N) Ga[(size_t)n * COLS_A + col] = (unsigned short)f2bf(acc[r]);
            }
        } else {
            const int c = col - COLS_A;
#pragma unroll
            for (int r = 0; r < 4; ++r) {
                const int n = mrow + r;
                if (n < N) Pb[(size_t)n * COLS_B + c] = acc[r];
            }
        }
    }
}

// ---------------- combined aggregation: out = [relu](mean_gather(Gbf16) + P) ----------------
// CHW/8 lanes per node (short8 = 8 bf16 channels per lane); fp32 accumulate.
template <int CHW, bool RELU>
__global__ __launch_bounds__(256) void k_agg_comb(const unsigned short* __restrict__ G,
                                                  const float* __restrict__ P,
                                                  const int* __restrict__ start,
                                                  const int* __restrict__ cnt,
                                                  const int* __restrict__ eidx,
                                                  float* __restrict__ outp, int N) {
    constexpr int LPN = CHW / 8;       // lanes per node: 16 / 8
    constexpr int NPB = 256 / LPN;     // nodes per block: 16 / 32
    const int g = threadIdx.x / LPN;
    const int l = threadIdx.x % LPN;
    const int n = blockIdx.x * NPB + g;
    if (n >= N) return;
    const int s0 = start[n];
    const int d  = cnt[n];
    const int* __restrict__ ep = eidx + s0;
    const int co = l * 8;

    float acc[8];
#pragma unroll
    for (int j = 0; j < 8; ++j) acc[j] = 0.f;

    int i = 0;
    for (; i + 4 <= d; i += 4) {
        const int e0 = ep[i], e1 = ep[i + 1], e2 = ep[i + 2], e3 = ep[i + 3];
        const short8 v0 = *(const short8*)&G[(size_t)e0 * CHW + co];
        const short8 v1 = *(const short8*)&G[(size_t)e1 * CHW + co];
        const short8 v2 = *(const short8*)&G[(size_t)e2 * CHW + co];
        const short8 v3 = *(const short8*)&G[(size_t)e3 * CHW + co];
#pragma unroll
        for (int j = 0; j < 8; ++j)
            acc[j] += (b2f(v0[j]) + b2f(v1[j])) + (b2f(v2[j]) + b2f(v3[j]));
    }
    for (; i < d; ++i) {
        const short8 v = *(const short8*)&G[(size_t)ep[i] * CHW + co];
#pragma unroll
        for (int j = 0; j < 8; ++j) acc[j] += b2f(v[j]);
    }

    const float sc = 1.0f / (float)(d > 0 ? d : 1);
    const float4 p0 = *(const float4*)&P[(size_t)n * CHW + co];
    const float4 p1 = *(const float4*)&P[(size_t)n * CHW + co + 4];
    float4 r0, r1;
    r0.x = fmaf(acc[0], sc, p0.x); r0.y = fmaf(acc[1], sc, p0.y);
    r0.z = fmaf(acc[2], sc, p0.z); r0.w = fmaf(acc[3], sc, p0.w);
    r1.x = fmaf(acc[4], sc, p1.x); r1.y = fmaf(acc[5], sc, p1.y);
    r1.z = fmaf(acc[6], sc, p1.z); r1.w = fmaf(acc[7], sc, p1.w);
    if (RELU) {
        r0.x = fmaxf(r0.x, 0.f); r0.y = fmaxf(r0.y, 0.f);
        r0.z = fmaxf(r0.z, 0.f); r0.w = fmaxf(r0.w, 0.f);
        r1.x = fmaxf(r1.x, 0.f); r1.y = fmaxf(r1.y, 0.f);
        r1.z = fmaxf(r1.z, 0.f); r1.w = fmaxf(r1.w, 0.f);
    }
    *(float4*)&outp[(size_t)n * CHW + co] = r0;
    *(float4*)&outp[(size_t)n * CHW + co + 4] = r1;
}

// ---------------- launch ----------------

extern "C" void kernel_launch(void* const* d_in, const int* in_sizes, int n_in,
                              void* d_out, int out_size, void* d_ws, size_t ws_size,
                              hipStream_t stream) {
    const float* x   = (const float*)d_in[0];
    const int*   ei  = (const int*)d_in[1];
    const float* W1l = (const float*)d_in[2];
    const float* W1r = (const float*)d_in[3];
    const float* b1  = (const float*)d_in[4];
    const float* W2l = (const float*)d_in[5];
    const float* W2r = (const float*)d_in[6];
    const float* b2  = (const float*)d_in[7];
    float* out = (float*)d_out;

    const int N = in_sizes[0] / CH;
    const int E = in_sizes[1] / 2;
    const int* src = ei;
    const int* dst = ei + E;

    // workspace carve
    char* w = (char*)d_ws;
    size_t o = 0;
    int* cnt     = (int*)(w + o); o += (size_t)N * 4;
    int* start   = (int*)(w + o); o += (size_t)N * 4;
    int* cursor  = (int*)(w + o); o += (size_t)N * 4;
    int* counter = (int*)(w + o); o += 16;
    int* eidx    = (int*)(w + o); o += (size_t)E * 4;
    short* pw1h  = (short*)(w + o); o += 32768 * 2;   // 128x256 bf16 hi
    short* pw1l  = (short*)(w + o); o += 32768 * 2;
    short* pw2h  = (short*)(w + o); o += 16384 * 2;   // 128x128 bf16 hi
    short* pw2l  = (short*)(w + o); o += 16384 * 2;
    unsigned short* bufG = (unsigned short*)(w + o); o += (size_t)N * CH * 2;  // g1 bf16; later g2 bf16
    float* bufP1 = (float*)(w + o); o += (size_t)N * CH * 4;  // p1 / h (in-place)
    float* bufP2 = (float*)(w + o); o += (size_t)N * 64 * 4;  // p2
    (void)ws_size; (void)n_in; (void)out_size;

    unsigned short* g1 = bufG;
    float* p1 = bufP1;         // h written in place over p1 (same-element RMW)
    float* h  = bufP1;
    unsigned short* g2 = bufG; // g1 dead after agg1
    float* p2 = bufP2;

    const int TB = 256;
    const int zb = (N + TB - 1) / TB;
    const int gb = (N + 63) / 64;

    // W pre-pack (L2-resident fragment-order hi/lo bf16)
    hipLaunchKernelGGL(k_pack, dim3(128), dim3(TB), 0, stream, W1l, W1r, 128, pw1h, pw1l);
    hipLaunchKernelGGL(k_pack, dim3(64),  dim3(TB), 0, stream, W2l, W2r, 64,  pw2h, pw2l);

    // CSR
    hipLaunchKernelGGL(k_zero,  dim3(zb),   dim3(TB), 0, stream, cnt, counter, N);
    hipLaunchKernelGGL(k_count, dim3(2048), dim3(TB), 0, stream, dst, E, cnt);
    hipLaunchKernelGGL(k_alloc, dim3(zb),   dim3(TB), 0, stream, cnt, start, cursor, counter, N);
    hipLaunchKernelGGL(k_fill,  dim3(2048), dim3(TB), 0, stream, src, dst, E, cursor, eidx);

    // layer 1: g1 = x@W1l (bf16), p1 = x@W1r + b1 ; h = relu(mean(g1) + p1)
    hipLaunchKernelGGL((k_gemm_mfma<128, 128>), dim3(gb), dim3(TB), 0, stream,
                       x, pw1h, pw1l, b1, g1, p1, N);
    hipLaunchKernelGGL((k_agg_comb<128, true>), dim3((N + 15) / 16), dim3(TB), 0, stream,
                       g1, p1, start, cnt, eidx, h, N);
    // layer 2: g2 = h@W2l (bf16), p2 = h@W2r + b2 ; out = mean(g2) + p2
    hipLaunchKernelGGL((k_gemm_mfma<64, 64>), dim3(gb), dim3(TB), 0, stream,
                       h, pw2h, pw2l, b2, g2, p2, N);
    hipLaunchKernelGGL((k_agg_comb<64, false>), dim3((N + 31) / 32), dim3(TB), 0, stream,
                       g2, p2, start, cnt, eidx, out, N);
}

// Round 6
// 371.228 us; speedup vs baseline: 2.3863x; 1.0135x over previous
//
#include <hip/hip_runtime.h>

// GraphSAGE 2-layer: N=100k, E=800k, 128->128(relu)->64. fp32 in/out.
// R5: GEMM restructure — 32 rows/wave (B reuse x2), split-accumulator MFMA
// chains (4 independent deps instead of 1x12 serial), LDS-staged coalesced
// bf16 Ga stores. Setup kernels fused (pack W1+W2 + zero cnt).
// Structure:
//   gemm1: g1(bf16) = x@W1l, p1 = x@W1r + b1 ; agg1: h = relu(mean(g1)+p1)
//   gemm2: g2(bf16) = h@W2l, p2 = h@W2r + b2 ; agg2: out = mean(g2)+p2

#define CH 128

typedef short short8 __attribute__((ext_vector_type(8)));
typedef float f32x4 __attribute__((ext_vector_type(4)));

__device__ __forceinline__ short f2bf(float x) {        // RNE fp32->bf16
    unsigned u = __float_as_uint(x);
    unsigned r = u + 0x7FFFu + ((u >> 16) & 1u);
    return (short)(r >> 16);
}
__device__ __forceinline__ float b2f(short s) {
    return __uint_as_float(((unsigned)(unsigned short)s) << 16);
}

// ---------------- fused setup: pack W1,W2 to B-frag order + zero cnt/counter ----------------
// Pack layout: idx = ((ct*4 + kt)*64 + lane)*8 + j ; c = ct*16 + (lane&15),
// k = kt*32 + (lane>>4)*8 + j ; cols = [Wa | Wb] (C2 each).
__device__ __forceinline__ void pack_one(const float* __restrict__ Wa, const float* __restrict__ Wb,
                                         int C2, short* __restrict__ hi, short* __restrict__ lo, int idx) {
    int j    = idx & 7;
    int lane = (idx >> 3) & 63;
    int kt   = (idx >> 9) & 3;
    int ct   = idx >> 11;
    int c = ct * 16 + (lane & 15);
    int k = kt * 32 + (lane >> 4) * 8 + j;
    float w = (c < C2) ? Wa[k * C2 + c] : Wb[k * C2 + (c - C2)];
    short h = f2bf(w);
    hi[idx] = h;
    lo[idx] = f2bf(w - b2f(h));
}

__global__ __launch_bounds__(256) void k_setup(const float* __restrict__ W1l, const float* __restrict__ W1r,
                                               const float* __restrict__ W2l, const float* __restrict__ W2r,
                                               short* __restrict__ pw1h, short* __restrict__ pw1l,
                                               short* __restrict__ pw2h, short* __restrict__ pw2l,
                                               int* __restrict__ cnt, int* __restrict__ counter, int N) {
    int idx = blockIdx.x * 256 + threadIdx.x;
    if (idx < 32768)      pack_one(W1l, W1r, 128, pw1h, pw1l, idx);
    else if (idx < 49152) pack_one(W2l, W2r, 64, pw2h, pw2l, idx - 32768);
    if (idx < N) cnt[idx] = 0;
    if (idx == 0) *counter = 0;
}

// ---------------- CSR build ----------------

__global__ __launch_bounds__(256) void k_count(const int* __restrict__ dst, int E, int* __restrict__ cnt) {
    int stride = gridDim.x * blockDim.x;
    for (int e = blockIdx.x * blockDim.x + threadIdx.x; e < E; e += stride)
        atomicAdd(&cnt[dst[e]], 1);
}

__global__ __launch_bounds__(256) void k_alloc(const int* __restrict__ cnt, int* __restrict__ start,
                                               int* __restrict__ cursor, int* __restrict__ counter, int N) {
    int n = blockIdx.x * blockDim.x + threadIdx.x;
    int lane = threadIdx.x & 63;
    int d = (n < N) ? cnt[n] : 0;
    int x = d;
#pragma unroll
    for (int o = 1; o < 64; o <<= 1) {
        int y = __shfl_up(x, o);
        if (lane >= o) x += y;
    }
    int total = __shfl(x, 63);
    int base = 0;
    if (lane == 63) base = atomicAdd(counter, total);
    base = __shfl(base, 63);
    int st = base + x - d;
    if (n < N) { start[n] = st; cursor[n] = st; }
}

__global__ __launch_bounds__(256) void k_fill(const int* __restrict__ src, const int* __restrict__ dst, int E,
                                              int* __restrict__ cursor, int* __restrict__ eidx) {
    int stride = gridDim.x * blockDim.x;
    for (int e = blockIdx.x * blockDim.x + threadIdx.x; e < E; e += stride) {
        int p = atomicAdd(&cursor[dst[e]], 1);
        eidx[p] = src[e];
    }
}

// ---------------- split-bf16 MFMA dual GEMM ----------------
// Block = 4 waves x 32 rows = 128 rows. Wave: two 16-row A-sets sharing B-frags.
// accA = Ahi@Bhi, accB = Alo@Bhi + Ahi@Blo (independent chains), summed at end.
// Ga (bf16) staged in wave-private padded LDS, flushed as coalesced dwordx4.
template <int COLS_A, int COLS_B>
__global__ __launch_bounds__(256) void k_gemm_mfma(const float* __restrict__ X,
                                                   const short* __restrict__ pHi,
                                                   const short* __restrict__ pLo,
                                                   const float* __restrict__ bias,
                                                   unsigned short* __restrict__ Ga,
                                                   float* __restrict__ Pb, int N) {
    constexpr int CTA = COLS_A / 16;
    constexpr int CT  = (COLS_A + COLS_B) / 16;
    constexpr int GB      = COLS_A * 2;   // Ga row bytes (bf16)
    constexpr int GSTRIDE = GB + 8;       // pad: rotates banks every 4 rows
    __shared__ alignas(16) char lds_g[4 * 32 * GSTRIDE];

    const int lane = threadIdx.x & 63;
    const int wv   = threadIdx.x >> 6;
    const int n0   = blockIdx.x * 128 + wv * 32;
    char* __restrict__ lg = lds_g + wv * 32 * GSTRIDE;

    // A-frags for two row-sets: lane holds A[lane&15][(lane>>4)*8 + j] per kt.
    short8 Ahi[2][4], Alo[2][4];
#pragma unroll
    for (int s = 0; s < 2; ++s) {
        int arow = n0 + s * 16 + (lane & 15);
        if (arow >= N) arow = N - 1;                    // clamped load, stores predicated
        const float* __restrict__ xr = X + (size_t)arow * CH + (lane >> 4) * 8;
#pragma unroll
        for (int kt = 0; kt < 4; ++kt) {
            const float4 a0 = *(const float4*)(xr + kt * 32);
            const float4 a1 = *(const float4*)(xr + kt * 32 + 4);
            const float av[8] = {a0.x, a0.y, a0.z, a0.w, a1.x, a1.y, a1.z, a1.w};
#pragma unroll
            for (int j = 0; j < 8; ++j) {
                const short h = f2bf(av[j]);
                Ahi[s][kt][j] = h;
                Alo[s][kt][j] = f2bf(av[j] - b2f(h));
            }
        }
    }

    const int ncol  = lane & 15;          // D col within tile
    const int rbase = (lane >> 4) * 4;    // D row base within 16

#pragma unroll
    for (int ct = 0; ct < CT; ++ct) {
        f32x4 accA[2], accB[2];
        {
            float bv = 0.f;
            if (ct >= CTA) bv = bias[(ct - CTA) * 16 + ncol];
#pragma unroll
            for (int s = 0; s < 2; ++s) {
                accA[s][0] = bv; accA[s][1] = bv; accA[s][2] = bv; accA[s][3] = bv;
                accB[s][0] = 0.f; accB[s][1] = 0.f; accB[s][2] = 0.f; accB[s][3] = 0.f;
            }
        }
#pragma unroll
        for (int kt = 0; kt < 4; ++kt) {
            const size_t fo = ((size_t)(ct * 4 + kt) * 64 + lane) * 8;
            const short8 bh = *(const short8*)(pHi + fo);
            const short8 bl = *(const short8*)(pLo + fo);
#pragma unroll
            for (int s = 0; s < 2; ++s) {
                accA[s] = __builtin_amdgcn_mfma_f32_16x16x32_bf16(Ahi[s][kt], bh, accA[s], 0, 0, 0);
                accB[s] = __builtin_amdgcn_mfma_f32_16x16x32_bf16(Alo[s][kt], bh, accB[s], 0, 0, 0);
                accB[s] = __builtin_amdgcn_mfma_f32_16x16x32_bf16(Ahi[s][kt], bl, accB[s], 0, 0, 0);
            }
        }
        if (ct < CTA) {
            // stage bf16 tile into wave-private LDS (flushed coalesced later)
#pragma unroll
            for (int s = 0; s < 2; ++s)
#pragma unroll
                for (int r = 0; r < 4; ++r) {
                    const int row = s * 16 + rbase + r;
                    *(unsigned short*)(lg + row * GSTRIDE + (ct * 16 + ncol) * 2) =
                        (unsigned short)f2bf(accA[s][r] + accB[s][r]);
                }
        } else {
            const int c = (ct - CTA) * 16 + ncol;
#pragma unroll
            for (int s = 0; s < 2; ++s)
#pragma unroll
                for (int r = 0; r < 4; ++r) {
                    const int n = n0 + s * 16 + rbase + r;
                    if (n < N) Pb[(size_t)n * COLS_B + c] = accA[s][r] + accB[s][r];
                }
        }
    }

    __syncthreads();   // LDS writes visible (cross-lane reads below)

    // flush Ga: each iter writes RPI full rows, fully coalesced
    constexpr int LPR = GB / 16;      // lanes per row (16B each): 16 / 8
    constexpr int RPI = 64 / LPR;     // rows per iter: 4 / 8
    const int lr = lane % LPR;
    const int rw = lane / LPR;
#pragma unroll
    for (int it = 0; it < 32 / RPI; ++it) {
        const int row = it * RPI + rw;
        const int n = n0 + row;
        if (n < N) {
            const short8 v = *(const short8*)(lg + row * GSTRIDE + lr * 16);
            *(short8*)(Ga + (size_t)n * COLS_A + lr * 8) = v;
        }
    }
}

// ---------------- combined aggregation: out = [relu](mean_gather(Gbf16) + P) ----------------
template <int CHW, bool RELU>
__global__ __launch_bounds__(256) void k_agg_comb(const unsigned short* __restrict__ G,
                                                  const float* __restrict__ P,
                                                  const int* __restrict__ start,
                                                  const int* __restrict__ cnt,
                                                  const int* __restrict__ eidx,
                                                  float* __restrict__ outp, int N) {
    constexpr int LPN = CHW / 8;       // lanes per node: 16 / 8
    constexpr int NPB = 256 / LPN;     // nodes per block: 16 / 32
    const int g = threadIdx.x / LPN;
    const int l = threadIdx.x % LPN;
    const int n = blockIdx.x * NPB + g;
    if (n >= N) return;
    const int s0 = start[n];
    const int d  = cnt[n];
    const int* __restrict__ ep = eidx + s0;
    const int co = l * 8;

    float acc[8];
#pragma unroll
    for (int j = 0; j < 8; ++j) acc[j] = 0.f;

    int i = 0;
    for (; i + 4 <= d; i += 4) {
        const int e0 = ep[i], e1 = ep[i + 1], e2 = ep[i + 2], e3 = ep[i + 3];
        const short8 v0 = *(const short8*)&G[(size_t)e0 * CHW + co];
        const short8 v1 = *(const short8*)&G[(size_t)e1 * CHW + co];
        const short8 v2 = *(const short8*)&G[(size_t)e2 * CHW + co];
        const short8 v3 = *(const short8*)&G[(size_t)e3 * CHW + co];
#pragma unroll
        for (int j = 0; j < 8; ++j)
            acc[j] += (b2f(v0[j]) + b2f(v1[j])) + (b2f(v2[j]) + b2f(v3[j]));
    }
    for (; i < d; ++i) {
        const short8 v = *(const short8*)&G[(size_t)ep[i] * CHW + co];
#pragma unroll
        for (int j = 0; j < 8; ++j) acc[j] += b2f(v[j]);
    }

    const float sc = 1.0f / (float)(d > 0 ? d : 1);
    const float4 p0 = *(const float4*)&P[(size_t)n * CHW + co];
    const float4 p1 = *(const float4*)&P[(size_t)n * CHW + co + 4];
    float4 r0, r1;
    r0.x = fmaf(acc[0], sc, p0.x); r0.y = fmaf(acc[1], sc, p0.y);
    r0.z = fmaf(acc[2], sc, p0.z); r0.w = fmaf(acc[3], sc, p0.w);
    r1.x = fmaf(acc[4], sc, p1.x); r1.y = fmaf(acc[5], sc, p1.y);
    r1.z = fmaf(acc[6], sc, p1.z); r1.w = fmaf(acc[7], sc, p1.w);
    if (RELU) {
        r0.x = fmaxf(r0.x, 0.f); r0.y = fmaxf(r0.y, 0.f);
        r0.z = fmaxf(r0.z, 0.f); r0.w = fmaxf(r0.w, 0.f);
        r1.x = fmaxf(r1.x, 0.f); r1.y = fmaxf(r1.y, 0.f);
        r1.z = fmaxf(r1.z, 0.f); r1.w = fmaxf(r1.w, 0.f);
    }
    *(float4*)&outp[(size_t)n * CHW + co] = r0;
    *(float4*)&outp[(size_t)n * CHW + co + 4] = r1;
}

// ---------------- launch ----------------

extern "C" void kernel_launch(void* const* d_in, const int* in_sizes, int n_in,
                              void* d_out, int out_size, void* d_ws, size_t ws_size,
                              hipStream_t stream) {
    const float* x   = (const float*)d_in[0];
    const int*   ei  = (const int*)d_in[1];
    const float* W1l = (const float*)d_in[2];
    const float* W1r = (const float*)d_in[3];
    const float* b1  = (const float*)d_in[4];
    const float* W2l = (const float*)d_in[5];
    const float* W2r = (const float*)d_in[6];
    const float* b2  = (const float*)d_in[7];
    float* out = (float*)d_out;

    const int N = in_sizes[0] / CH;
    const int E = in_sizes[1] / 2;
    const int* src = ei;
    const int* dst = ei + E;

    // workspace carve
    char* w = (char*)d_ws;
    size_t o = 0;
    int* cnt     = (int*)(w + o); o += (size_t)N * 4;
    int* start   = (int*)(w + o); o += (size_t)N * 4;
    int* cursor  = (int*)(w + o); o += (size_t)N * 4;
    int* counter = (int*)(w + o); o += 16;
    int* eidx    = (int*)(w + o); o += (size_t)E * 4;
    short* pw1h  = (short*)(w + o); o += 32768 * 2;   // 128x256 bf16 hi
    short* pw1l  = (short*)(w + o); o += 32768 * 2;
    short* pw2h  = (short*)(w + o); o += 16384 * 2;   // 128x128 bf16 hi
    short* pw2l  = (short*)(w + o); o += 16384 * 2;
    unsigned short* bufG = (unsigned short*)(w + o); o += (size_t)N * CH * 2;  // g1 bf16; later g2 bf16
    float* bufP1 = (float*)(w + o); o += (size_t)N * CH * 4;  // p1 / h (in-place)
    float* bufP2 = (float*)(w + o); o += (size_t)N * 64 * 4;  // p2
    (void)ws_size; (void)n_in; (void)out_size;

    unsigned short* g1 = bufG;
    float* p1 = bufP1;         // h written in place over p1 (same-element RMW)
    float* h  = bufP1;
    unsigned short* g2 = bufG; // g1 dead after agg1
    float* p2 = bufP2;

    const int TB = 256;
    const int zb = (N + TB - 1) / TB;       // 391 also covers 49152 pack elems
    const int gb = (N + 127) / 128;

    hipLaunchKernelGGL(k_setup, dim3(zb), dim3(TB), 0, stream,
                       W1l, W1r, W2l, W2r, pw1h, pw1l, pw2h, pw2l, cnt, counter, N);
    hipLaunchKernelGGL(k_count, dim3(2048), dim3(TB), 0, stream, dst, E, cnt);
    hipLaunchKernelGGL(k_alloc, dim3(zb),   dim3(TB), 0, stream, cnt, start, cursor, counter, N);
    hipLaunchKernelGGL(k_fill,  dim3(2048), dim3(TB), 0, stream, src, dst, E, cursor, eidx);

    // layer 1: g1 = x@W1l (bf16), p1 = x@W1r + b1 ; h = relu(mean(g1) + p1)
    hipLaunchKernelGGL((k_gemm_mfma<128, 128>), dim3(gb), dim3(TB), 0, stream,
                       x, pw1h, pw1l, b1, g1, p1, N);
    hipLaunchKernelGGL((k_agg_comb<128, true>), dim3((N + 15) / 16), dim3(TB), 0, stream,
                       g1, p1, start, cnt, eidx, h, N);
    // layer 2: g2 = h@W2l (bf16), p2 = h@W2r + b2 ; out = mean(g2) + p2
    hipLaunchKernelGGL((k_gemm_mfma<64, 64>), dim3(gb), dim3(TB), 0, stream,
                       h, pw2h, pw2l, b2, g2, p2, N);
    hipLaunchKernelGGL((k_agg_comb<64, false>), dim3((N + 31) / 32), dim3(TB), 0, stream,
                       g2, p2, start, cnt, eidx, out, N);
}

// Round 7
// 363.353 us; speedup vs baseline: 2.4380x; 1.0217x over previous
//
#include <hip/hip_runtime.h>

// GraphSAGE 2-layer: N=100k, E=800k, 128->128(relu)->64. fp32 in/out.
// R6: persistent-B GEMM — each wave holds its col-tile slice of the packed
// bf16 hi/lo W panel in REGISTERS (loaded once), grid-strides over 16-row
// chunks. Kills the per-wave B-reload latency that pinned R3/R5 at ~62us.
// Structure:
//   gemm1: g1(bf16) = x@W1l, p1 = x@W1r + b1 ; agg1: h = relu(mean(g1)+p1)
//   gemm2: g2(bf16) = h@W2l, p2 = h@W2r + b2 ; agg2: out = mean(g2)+p2

#define CH 128

typedef short short8 __attribute__((ext_vector_type(8)));
typedef float f32x4 __attribute__((ext_vector_type(4)));

__device__ __forceinline__ short f2bf(float x) {        // RNE fp32->bf16
    unsigned u = __float_as_uint(x);
    unsigned r = u + 0x7FFFu + ((u >> 16) & 1u);
    return (short)(r >> 16);
}
__device__ __forceinline__ float b2f(short s) {
    return __uint_as_float(((unsigned)(unsigned short)s) << 16);
}

// ---------------- fused setup: pack W1,W2 to B-frag order + zero cnt/counter ----------------
// Pack layout: idx = ((ct*4 + kt)*64 + lane)*8 + j ; c = ct*16 + (lane&15),
// k = kt*32 + (lane>>4)*8 + j ; cols = [Wa | Wb] (C2 each).
__device__ __forceinline__ void pack_one(const float* __restrict__ Wa, const float* __restrict__ Wb,
                                         int C2, short* __restrict__ hi, short* __restrict__ lo, int idx) {
    int j    = idx & 7;
    int lane = (idx >> 3) & 63;
    int kt   = (idx >> 9) & 3;
    int ct   = idx >> 11;
    int c = ct * 16 + (lane & 15);
    int k = kt * 32 + (lane >> 4) * 8 + j;
    float w = (c < C2) ? Wa[k * C2 + c] : Wb[k * C2 + (c - C2)];
    short h = f2bf(w);
    hi[idx] = h;
    lo[idx] = f2bf(w - b2f(h));
}

__global__ __launch_bounds__(256) void k_setup(const float* __restrict__ W1l, const float* __restrict__ W1r,
                                               const float* __restrict__ W2l, const float* __restrict__ W2r,
                                               short* __restrict__ pw1h, short* __restrict__ pw1l,
                                               short* __restrict__ pw2h, short* __restrict__ pw2l,
                                               int* __restrict__ cnt, int* __restrict__ counter, int N) {
    int idx = blockIdx.x * 256 + threadIdx.x;
    if (idx < 32768)      pack_one(W1l, W1r, 128, pw1h, pw1l, idx);
    else if (idx < 49152) pack_one(W2l, W2r, 64, pw2h, pw2l, idx - 32768);
    if (idx < N) cnt[idx] = 0;
    if (idx == 0) *counter = 0;
}

// ---------------- CSR build ----------------

__global__ __launch_bounds__(256) void k_count(const int* __restrict__ dst, int E, int* __restrict__ cnt) {
    int stride = gridDim.x * blockDim.x;
    for (int e = blockIdx.x * blockDim.x + threadIdx.x; e < E; e += stride)
        atomicAdd(&cnt[dst[e]], 1);
}

__global__ __launch_bounds__(256) void k_alloc(const int* __restrict__ cnt, int* __restrict__ start,
                                               int* __restrict__ cursor, int* __restrict__ counter, int N) {
    int n = blockIdx.x * blockDim.x + threadIdx.x;
    int lane = threadIdx.x & 63;
    int d = (n < N) ? cnt[n] : 0;
    int x = d;
#pragma unroll
    for (int o = 1; o < 64; o <<= 1) {
        int y = __shfl_up(x, o);
        if (lane >= o) x += y;
    }
    int total = __shfl(x, 63);
    int base = 0;
    if (lane == 63) base = atomicAdd(counter, total);
    base = __shfl(base, 63);
    int st = base + x - d;
    if (n < N) { start[n] = st; cursor[n] = st; }
}

__global__ __launch_bounds__(256) void k_fill(const int* __restrict__ src, const int* __restrict__ dst, int E,
                                              int* __restrict__ cursor, int* __restrict__ eidx) {
    int stride = gridDim.x * blockDim.x;
    for (int e = blockIdx.x * blockDim.x + threadIdx.x; e < E; e += stride) {
        int p = atomicAdd(&cursor[dst[e]], 1);
        eidx[p] = src[e];
    }
}

// ---------------- persistent-B split-bf16 MFMA dual GEMM ----------------
// Wave w holds B-frags for col-tiles [w*CTW, (w+1)*CTW) in registers (hi+lo),
// loaded once. Block grid-strides over 16-row chunks of X; per chunk: load A
// (coalesced), hi/lo split, CTW col-tiles x 4 kt x 3 MFMA, store.
// accA = Ahi@Bhi (+bias), accB = Alo@Bhi + Ahi@Blo; sum at store.
template <int COLS_A, int COLS_B>
__global__ __launch_bounds__(256, 2) void k_gemm_persist(const float* __restrict__ X,
                                                         const short* __restrict__ pHi,
                                                         const short* __restrict__ pLo,
                                                         const float* __restrict__ bias,
                                                         unsigned short* __restrict__ Ga,
                                                         float* __restrict__ Pb,
                                                         int N, int nchunks) {
    constexpr int CT  = (COLS_A + COLS_B) / 16;
    constexpr int CTW = CT / 4;          // col-tiles per wave: 4 (L1), 2 (L2)
    constexpr int CTA = COLS_A / 16;
    const int lane  = threadIdx.x & 63;
    const int wv    = threadIdx.x >> 6;
    const int ncol  = lane & 15;         // D col within tile / A row within chunk
    const int rbase = (lane >> 4) * 4;   // D row base
    const int koff  = (lane >> 4) * 8;   // A k-slice base

    // persistent B fragments + bias
    short8 Bh[CTW][4], Bl[CTW][4];
    float bv[CTW];
#pragma unroll
    for (int c = 0; c < CTW; ++c) {
        const int ct = wv * CTW + c;
        bv[c] = (ct >= CTA) ? bias[(ct - CTA) * 16 + ncol] : 0.f;
#pragma unroll
        for (int kt = 0; kt < 4; ++kt) {
            const size_t fo = ((size_t)(ct * 4 + kt) * 64 + lane) * 8;
            Bh[c][kt] = *(const short8*)(pHi + fo);
            Bl[c][kt] = *(const short8*)(pLo + fo);
        }
    }

#pragma unroll 1
    for (int chunk = blockIdx.x; chunk < nchunks; chunk += gridDim.x) {
        const int n0 = chunk * 16;
        // A-frag: lane holds A[n0 + ncol][koff + kt*32 + j]
        short8 Ahi[4], Alo[4];
        {
            int arow = n0 + ncol;
            if (arow >= N) arow = N - 1;             // clamped load, stores predicated
            const float* __restrict__ xr = X + (size_t)arow * CH + koff;
#pragma unroll
            for (int kt = 0; kt < 4; ++kt) {
                const float4 a0 = *(const float4*)(xr + kt * 32);
                const float4 a1 = *(const float4*)(xr + kt * 32 + 4);
                const float av[8] = {a0.x, a0.y, a0.z, a0.w, a1.x, a1.y, a1.z, a1.w};
#pragma unroll
                for (int j = 0; j < 8; ++j) {
                    const short h = f2bf(av[j]);
                    Ahi[kt][j] = h;
                    Alo[kt][j] = f2bf(av[j] - b2f(h));
                }
            }
        }

        const int mrow = n0 + rbase;
#pragma unroll
        for (int c = 0; c < CTW; ++c) {
            const int ct = wv * CTW + c;
            f32x4 accA, accB;
            accA[0] = bv[c]; accA[1] = bv[c]; accA[2] = bv[c]; accA[3] = bv[c];
            accB[0] = 0.f;   accB[1] = 0.f;   accB[2] = 0.f;   accB[3] = 0.f;
#pragma unroll
            for (int kt = 0; kt < 4; ++kt) {
                accA = __builtin_amdgcn_mfma_f32_16x16x32_bf16(Ahi[kt], Bh[c][kt], accA, 0, 0, 0);
                accB = __builtin_amdgcn_mfma_f32_16x16x32_bf16(Alo[kt], Bh[c][kt], accB, 0, 0, 0);
                accB = __builtin_amdgcn_mfma_f32_16x16x32_bf16(Ahi[kt], Bl[c][kt], accB, 0, 0, 0);
            }
            if (ct < CTA) {
                const int col = ct * 16 + ncol;
#pragma unroll
                for (int r = 0; r < 4; ++r) {
                    const int n = mrow + r;
                    if (n < N)
                        Ga[(size_t)n * COLS_A + col] = (unsigned short)f2bf(accA[r] + accB[r]);
                }
            } else {
                const int col = (ct - CTA) * 16 + ncol;
#pragma unroll
                for (int r = 0; r < 4; ++r) {
                    const int n = mrow + r;
                    if (n < N)
                        Pb[(size_t)n * COLS_B + col] = accA[r] + accB[r];
                }
            }
        }
    }
}

// ---------------- combined aggregation: out = [relu](mean_gather(Gbf16) + P) ----------------
template <int CHW, bool RELU>
__global__ __launch_bounds__(256) void k_agg_comb(const unsigned short* __restrict__ G,
                                                  const float* __restrict__ P,
                                                  const int* __restrict__ start,
                                                  const int* __restrict__ cnt,
                                                  const int* __restrict__ eidx,
                                                  float* __restrict__ outp, int N) {
    constexpr int LPN = CHW / 8;       // lanes per node: 16 / 8
    constexpr int NPB = 256 / LPN;     // nodes per block: 16 / 32
    const int g = threadIdx.x / LPN;
    const int l = threadIdx.x % LPN;
    const int n = blockIdx.x * NPB + g;
    if (n >= N) return;
    const int s0 = start[n];
    const int d  = cnt[n];
    const int* __restrict__ ep = eidx + s0;
    const int co = l * 8;

    float acc[8];
#pragma unroll
    for (int j = 0; j < 8; ++j) acc[j] = 0.f;

    int i = 0;
    for (; i + 4 <= d; i += 4) {
        const int e0 = ep[i], e1 = ep[i + 1], e2 = ep[i + 2], e3 = ep[i + 3];
        const short8 v0 = *(const short8*)&G[(size_t)e0 * CHW + co];
        const short8 v1 = *(const short8*)&G[(size_t)e1 * CHW + co];
        const short8 v2 = *(const short8*)&G[(size_t)e2 * CHW + co];
        const short8 v3 = *(const short8*)&G[(size_t)e3 * CHW + co];
#pragma unroll
        for (int j = 0; j < 8; ++j)
            acc[j] += (b2f(v0[j]) + b2f(v1[j])) + (b2f(v2[j]) + b2f(v3[j]));
    }
    for (; i < d; ++i) {
        const short8 v = *(const short8*)&G[(size_t)ep[i] * CHW + co];
#pragma unroll
        for (int j = 0; j < 8; ++j) acc[j] += b2f(v[j]);
    }

    const float sc = 1.0f / (float)(d > 0 ? d : 1);
    const float4 p0 = *(const float4*)&P[(size_t)n * CHW + co];
    const float4 p1 = *(const float4*)&P[(size_t)n * CHW + co + 4];
    float4 r0, r1;
    r0.x = fmaf(acc[0], sc, p0.x); r0.y = fmaf(acc[1], sc, p0.y);
    r0.z = fmaf(acc[2], sc, p0.z); r0.w = fmaf(acc[3], sc, p0.w);
    r1.x = fmaf(acc[4], sc, p1.x); r1.y = fmaf(acc[5], sc, p1.y);
    r1.z = fmaf(acc[6], sc, p1.z); r1.w = fmaf(acc[7], sc, p1.w);
    if (RELU) {
        r0.x = fmaxf(r0.x, 0.f); r0.y = fmaxf(r0.y, 0.f);
        r0.z = fmaxf(r0.z, 0.f); r0.w = fmaxf(r0.w, 0.f);
        r1.x = fmaxf(r1.x, 0.f); r1.y = fmaxf(r1.y, 0.f);
        r1.z = fmaxf(r1.z, 0.f); r1.w = fmaxf(r1.w, 0.f);
    }
    *(float4*)&outp[(size_t)n * CHW + co] = r0;
    *(float4*)&outp[(size_t)n * CHW + co + 4] = r1;
}

// ---------------- launch ----------------

extern "C" void kernel_launch(void* const* d_in, const int* in_sizes, int n_in,
                              void* d_out, int out_size, void* d_ws, size_t ws_size,
                              hipStream_t stream) {
    const float* x   = (const float*)d_in[0];
    const int*   ei  = (const int*)d_in[1];
    const float* W1l = (const float*)d_in[2];
    const float* W1r = (const float*)d_in[3];
    const float* b1  = (const float*)d_in[4];
    const float* W2l = (const float*)d_in[5];
    const float* W2r = (const float*)d_in[6];
    const float* b2  = (const float*)d_in[7];
    float* out = (float*)d_out;

    const int N = in_sizes[0] / CH;
    const int E = in_sizes[1] / 2;
    const int* src = ei;
    const int* dst = ei + E;

    // workspace carve
    char* w = (char*)d_ws;
    size_t o = 0;
    int* cnt     = (int*)(w + o); o += (size_t)N * 4;
    int* start   = (int*)(w + o); o += (size_t)N * 4;
    int* cursor  = (int*)(w + o); o += (size_t)N * 4;
    int* counter = (int*)(w + o); o += 16;
    int* eidx    = (int*)(w + o); o += (size_t)E * 4;
    short* pw1h  = (short*)(w + o); o += 32768 * 2;   // 128x256 bf16 hi
    short* pw1l  = (short*)(w + o); o += 32768 * 2;
    short* pw2h  = (short*)(w + o); o += 16384 * 2;   // 128x128 bf16 hi
    short* pw2l  = (short*)(w + o); o += 16384 * 2;
    unsigned short* bufG = (unsigned short*)(w + o); o += (size_t)N * CH * 2;  // g1 bf16; later g2 bf16
    float* bufP1 = (float*)(w + o); o += (size_t)N * CH * 4;  // p1 / h (in-place)
    float* bufP2 = (float*)(w + o); o += (size_t)N * 64 * 4;  // p2
    (void)ws_size; (void)n_in; (void)out_size;

    unsigned short* g1 = bufG;
    float* p1 = bufP1;         // h written in place over p1 (same-element RMW)
    float* h  = bufP1;
    unsigned short* g2 = bufG; // g1 dead after agg1
    float* p2 = bufP2;

    const int TB = 256;
    const int zb = (N + TB - 1) / TB;       // 391 blocks also covers 49152 pack elems
    const int nchunks = (N + 15) / 16;      // 6250
    const int gpb = 512;                    // 2 blocks/CU, grid-stride chunks

    hipLaunchKernelGGL(k_setup, dim3(zb), dim3(TB), 0, stream,
                       W1l, W1r, W2l, W2r, pw1h, pw1l, pw2h, pw2l, cnt, counter, N);
    hipLaunchKernelGGL(k_count, dim3(2048), dim3(TB), 0, stream, dst, E, cnt);
    hipLaunchKernelGGL(k_alloc, dim3(zb),   dim3(TB), 0, stream, cnt, start, cursor, counter, N);
    hipLaunchKernelGGL(k_fill,  dim3(2048), dim3(TB), 0, stream, src, dst, E, cursor, eidx);

    // layer 1: g1 = x@W1l (bf16), p1 = x@W1r + b1 ; h = relu(mean(g1) + p1)
    hipLaunchKernelGGL((k_gemm_persist<128, 128>), dim3(gpb), dim3(TB), 0, stream,
                       x, pw1h, pw1l, b1, g1, p1, N, nchunks);
    hipLaunchKernelGGL((k_agg_comb<128, true>), dim3((N + 15) / 16), dim3(TB), 0, stream,
                       g1, p1, start, cnt, eidx, h, N);
    // layer 2: g2 = h@W2l (bf16), p2 = h@W2r + b2 ; out = mean(g2) + p2
    hipLaunchKernelGGL((k_gemm_persist<64, 64>), dim3(gpb), dim3(TB), 0, stream,
                       h, pw2h, pw2l, b2, g2, p2, N, nchunks);
    hipLaunchKernelGGL((k_agg_comb<64, false>), dim3((N + 31) / 32), dim3(TB), 0, stream,
                       g2, p2, start, cnt, eidx, out, N);
}

// Round 8
// 345.178 us; speedup vs baseline: 2.5664x; 1.0527x over previous
//
#include <hip/hip_runtime.h>

// GraphSAGE 2-layer: N=100k, E=800k, 128->128(relu)->64. fp32 in/out.
// R7: bf16 h-path. h stored bf16 (embedded in p1 buffer, stride 512B) ->
// gemm2 A-operand is EXACT bf16: 2-term MFMA, no A-convert. p2/g2 bf16.
// gemm1 keeps 3-term split-bf16 (RTZ hi + RNE lo residual).
//   gemm1: g1(bf16) = x@W1l, p1(f32) = x@W1r + b1
//   agg1 : h(bf16)  = relu(mean(g1) + p1)        [h in p1's buffer]
//   gemm2: g2(bf16) = h@W2l, p2(bf16) = h@W2r + b2
//   agg2 : out(f32) = mean(g2) + p2

#define CH 128

typedef short short8 __attribute__((ext_vector_type(8)));
typedef float f32x4 __attribute__((ext_vector_type(4)));

__device__ __forceinline__ short f2bf(float x) {        // RNE fp32->bf16
    unsigned u = __float_as_uint(x);
    unsigned r = u + 0x7FFFu + ((u >> 16) & 1u);
    return (short)(r >> 16);
}
__device__ __forceinline__ float b2f(short s) {
    return __uint_as_float(((unsigned)(unsigned short)s) << 16);
}

// ---------------- CSR build ----------------

__global__ __launch_bounds__(256) void k_zero(int* __restrict__ cnt, int N) {
    int i = blockIdx.x * blockDim.x + threadIdx.x;
    if (i <= N) cnt[i] = 0;            // cnt[N] doubles as the alloc counter
}

// B-frag pack: idx = ((ct*4 + kt)*64 + lane)*8 + j ; c = ct*16 + (lane&15),
// k = kt*32 + (lane>>4)*8 + j ; cols = [Wa | Wb] (C2 each).
__device__ __forceinline__ void pack_one(const float* __restrict__ Wa, const float* __restrict__ Wb,
                                         int C2, short* __restrict__ hi, short* __restrict__ lo, int idx) {
    int j    = idx & 7;
    int lane = (idx >> 3) & 63;
    int kt   = (idx >> 9) & 3;
    int ct   = idx >> 11;
    int c = ct * 16 + (lane & 15);
    int k = kt * 32 + (lane >> 4) * 8 + j;
    float w = (c < C2) ? Wa[k * C2 + c] : Wb[k * C2 + (c - C2)];
    short h = f2bf(w);
    hi[idx] = h;
    lo[idx] = f2bf(w - b2f(h));
}

__global__ __launch_bounds__(256) void k_count_pack(const int* __restrict__ dst, int E, int* __restrict__ cnt,
                                                    const float* __restrict__ W1l, const float* __restrict__ W1r,
                                                    const float* __restrict__ W2l, const float* __restrict__ W2r,
                                                    short* __restrict__ pw1h, short* __restrict__ pw1l,
                                                    short* __restrict__ pw2h, short* __restrict__ pw2l) {
    int gid = blockIdx.x * 256 + threadIdx.x;
    if (gid < 32768)      pack_one(W1l, W1r, 128, pw1h, pw1l, gid);
    else if (gid < 49152) pack_one(W2l, W2r, 64, pw2h, pw2l, gid - 32768);
    int stride = gridDim.x * blockDim.x;
    for (int e = gid; e < E; e += stride)
        atomicAdd(&cnt[dst[e]], 1);
}

__global__ __launch_bounds__(256) void k_alloc(const int* __restrict__ cnt, int* __restrict__ start,
                                               int* __restrict__ cursor, int* __restrict__ counter, int N) {
    int n = blockIdx.x * blockDim.x + threadIdx.x;
    int lane = threadIdx.x & 63;
    int d = (n < N) ? cnt[n] : 0;
    int x = d;
#pragma unroll
    for (int o = 1; o < 64; o <<= 1) {
        int y = __shfl_up(x, o);
        if (lane >= o) x += y;
    }
    int total = __shfl(x, 63);
    int base = 0;
    if (lane == 63) base = atomicAdd(counter, total);
    base = __shfl(base, 63);
    int st = base + x - d;
    if (n < N) { start[n] = st; cursor[n] = st; }
}

__global__ __launch_bounds__(256) void k_fill(const int* __restrict__ src, const int* __restrict__ dst, int E,
                                              int* __restrict__ cursor, int* __restrict__ eidx) {
    int stride = gridDim.x * blockDim.x;
    for (int e = blockIdx.x * blockDim.x + threadIdx.x; e < E; e += stride) {
        int p = atomicAdd(&cursor[dst[e]], 1);
        eidx[p] = src[e];
    }
}

// ---------------- gemm1: persistent-B, fp32 A with RTZ hi / RNE lo split ----------------
// Wave w holds B col-tiles [w*4,(w+1)*4) in regs. 3 MFMA terms.
__global__ __launch_bounds__(256, 2) void k_gemm1(const float* __restrict__ X,
                                                  const short* __restrict__ pHi,
                                                  const short* __restrict__ pLo,
                                                  const float* __restrict__ bias,
                                                  unsigned short* __restrict__ Ga,
                                                  float* __restrict__ Pb,
                                                  int N, int nchunks) {
    constexpr int CTW = 4, CTA = 8;
    const int lane  = threadIdx.x & 63;
    const int wv    = threadIdx.x >> 6;
    const int ncol  = lane & 15;
    const int rbase = (lane >> 4) * 4;
    const int koff  = (lane >> 4) * 8;

    short8 Bh[CTW][4], Bl[CTW][4];
    float bv[CTW];
#pragma unroll
    for (int c = 0; c < CTW; ++c) {
        const int ct = wv * CTW + c;
        bv[c] = (ct >= CTA) ? bias[(ct - CTA) * 16 + ncol] : 0.f;
#pragma unroll
        for (int kt = 0; kt < 4; ++kt) {
            const size_t fo = ((size_t)(ct * 4 + kt) * 64 + lane) * 8;
            Bh[c][kt] = *(const short8*)(pHi + fo);
            Bl[c][kt] = *(const short8*)(pLo + fo);
        }
    }

#pragma unroll 1
    for (int chunk = blockIdx.x; chunk < nchunks; chunk += gridDim.x) {
        const int n0 = chunk * 16;
        short8 Ahi[4], Alo[4];
        {
            int arow = n0 + ncol;
            if (arow >= N) arow = N - 1;
            const float* __restrict__ xr = X + (size_t)arow * CH + koff;
#pragma unroll
            for (int kt = 0; kt < 4; ++kt) {
                const float4 a0 = *(const float4*)(xr + kt * 32);
                const float4 a1 = *(const float4*)(xr + kt * 32 + 4);
                const float av[8] = {a0.x, a0.y, a0.z, a0.w, a1.x, a1.y, a1.z, a1.w};
#pragma unroll
                for (int j = 0; j < 8; ++j) {
                    const unsigned u = __float_as_uint(av[j]);
                    Ahi[kt][j] = (short)(u >> 16);                      // RTZ hi
                    Alo[kt][j] = f2bf(av[j] - __uint_as_float(u & 0xFFFF0000u));
                }
            }
        }

        const int mrow = n0 + rbase;
#pragma unroll
        for (int c = 0; c < CTW; ++c) {
            const int ct = wv * CTW + c;
            f32x4 accA, accB;
            accA[0] = bv[c]; accA[1] = bv[c]; accA[2] = bv[c]; accA[3] = bv[c];
            accB[0] = 0.f;   accB[1] = 0.f;   accB[2] = 0.f;   accB[3] = 0.f;
#pragma unroll
            for (int kt = 0; kt < 4; ++kt) {
                accA = __builtin_amdgcn_mfma_f32_16x16x32_bf16(Ahi[kt], Bh[c][kt], accA, 0, 0, 0);
                accB = __builtin_amdgcn_mfma_f32_16x16x32_bf16(Alo[kt], Bh[c][kt], accB, 0, 0, 0);
                accB = __builtin_amdgcn_mfma_f32_16x16x32_bf16(Ahi[kt], Bl[c][kt], accB, 0, 0, 0);
            }
            if (ct < CTA) {
                const int col = ct * 16 + ncol;
#pragma unroll
                for (int r = 0; r < 4; ++r) {
                    const int n = mrow + r;
                    if (n < N)
                        Ga[(size_t)n * 128 + col] = (unsigned short)f2bf(accA[r] + accB[r]);
                }
            } else {
                const int col = (ct - CTA) * 16 + ncol;
#pragma unroll
                for (int r = 0; r < 4; ++r) {
                    const int n = mrow + r;
                    if (n < N)
                        Pb[(size_t)n * 128 + col] = accA[r] + accB[r];
                }
            }
        }
    }
}

// ---------------- gemm2: persistent-B, EXACT bf16 A (h), 2-term MFMA ----------------
// A rows read from h (bf16, row stride 256 ushorts). g2/p2 outputs bf16.
__global__ __launch_bounds__(256, 4) void k_gemm2(const unsigned short* __restrict__ H,
                                                  const short* __restrict__ pHi,
                                                  const short* __restrict__ pLo,
                                                  const float* __restrict__ bias,
                                                  unsigned short* __restrict__ Ga,
                                                  unsigned short* __restrict__ Pb,
                                                  int N, int nchunks) {
    constexpr int CTW = 2, CTA = 4;
    const int lane  = threadIdx.x & 63;
    const int wv    = threadIdx.x >> 6;
    const int ncol  = lane & 15;
    const int rbase = (lane >> 4) * 4;
    const int koff  = (lane >> 4) * 8;

    short8 Bh[CTW][4], Bl[CTW][4];
    float bv[CTW];
#pragma unroll
    for (int c = 0; c < CTW; ++c) {
        const int ct = wv * CTW + c;
        bv[c] = (ct >= CTA) ? bias[(ct - CTA) * 16 + ncol] : 0.f;
#pragma unroll
        for (int kt = 0; kt < 4; ++kt) {
            const size_t fo = ((size_t)(ct * 4 + kt) * 64 + lane) * 8;
            Bh[c][kt] = *(const short8*)(pHi + fo);
            Bl[c][kt] = *(const short8*)(pLo + fo);
        }
    }

#pragma unroll 1
    for (int chunk = blockIdx.x; chunk < nchunks; chunk += gridDim.x) {
        const int n0 = chunk * 16;
        short8 Ah[4];
        {
            int arow = n0 + ncol;
            if (arow >= N) arow = N - 1;
            const unsigned short* __restrict__ hr = H + (size_t)arow * 256 + koff;
#pragma unroll
            for (int kt = 0; kt < 4; ++kt)
                Ah[kt] = *(const short8*)(hr + kt * 32);   // ch kt*32+koff.. (+8)
        }

        const int mrow = n0 + rbase;
#pragma unroll
        for (int c = 0; c < CTW; ++c) {
            const int ct = wv * CTW + c;
            f32x4 accA, accB;
            accA[0] = bv[c]; accA[1] = bv[c]; accA[2] = bv[c]; accA[3] = bv[c];
            accB[0] = 0.f;   accB[1] = 0.f;   accB[2] = 0.f;   accB[3] = 0.f;
#pragma unroll
            for (int kt = 0; kt < 4; ++kt) {
                accA = __builtin_amdgcn_mfma_f32_16x16x32_bf16(Ah[kt], Bh[c][kt], accA, 0, 0, 0);
                accB = __builtin_amdgcn_mfma_f32_16x16x32_bf16(Ah[kt], Bl[c][kt], accB, 0, 0, 0);
            }
            unsigned short* __restrict__ O = (ct < CTA) ? Ga : Pb;
            const int col = ((ct < CTA) ? ct : ct - CTA) * 16 + ncol;
#pragma unroll
            for (int r = 0; r < 4; ++r) {
                const int n = mrow + r;
                if (n < N)
                    O[(size_t)n * 64 + col] = (unsigned short)f2bf(accA[r] + accB[r]);
            }
        }
    }
}

// ---------------- aggregation: out = [relu](mean_gather(Gbf16) + P) ----------------
// PSTRIDE/OSTRIDE in elements of their storage type.
template <int CHW, bool RELU, bool PBF16, bool OBF16, int PSTRIDE, int OSTRIDE>
__global__ __launch_bounds__(256) void k_agg(const unsigned short* __restrict__ G,
                                             const void* __restrict__ Pv,
                                             const int* __restrict__ start,
                                             const int* __restrict__ cnt,
                                             const int* __restrict__ eidx,
                                             void* __restrict__ outv, int N) {
    constexpr int LPN = CHW / 8;       // lanes per node: 16 / 8
    constexpr int NPB = 256 / LPN;     // nodes per block: 16 / 32
    const int g = threadIdx.x / LPN;
    const int l = threadIdx.x % LPN;
    const int n = blockIdx.x * NPB + g;
    if (n >= N) return;
    const int s0 = start[n];
    const int d  = cnt[n];
    const int* __restrict__ ep = eidx + s0;
    const int co = l * 8;

    float acc[8];
#pragma unroll
    for (int j = 0; j < 8; ++j) acc[j] = 0.f;

    int i = 0;
    for (; i + 4 <= d; i += 4) {
        const int e0 = ep[i], e1 = ep[i + 1], e2 = ep[i + 2], e3 = ep[i + 3];
        const short8 v0 = *(const short8*)&G[(size_t)e0 * CHW + co];
        const short8 v1 = *(const short8*)&G[(size_t)e1 * CHW + co];
        const short8 v2 = *(const short8*)&G[(size_t)e2 * CHW + co];
        const short8 v3 = *(const short8*)&G[(size_t)e3 * CHW + co];
#pragma unroll
        for (int j = 0; j < 8; ++j)
            acc[j] += (b2f(v0[j]) + b2f(v1[j])) + (b2f(v2[j]) + b2f(v3[j]));
    }
    for (; i < d; ++i) {
        const short8 v = *(const short8*)&G[(size_t)ep[i] * CHW + co];
#pragma unroll
        for (int j = 0; j < 8; ++j) acc[j] += b2f(v[j]);
    }

    const float sc = 1.0f / (float)(d > 0 ? d : 1);
    float r[8];
    if (PBF16) {
        const short8 pp = *(const short8*)((const unsigned short*)Pv + (size_t)n * PSTRIDE + co);
#pragma unroll
        for (int j = 0; j < 8; ++j) r[j] = fmaf(acc[j], sc, b2f(pp[j]));
    } else {
        const float* __restrict__ P = (const float*)Pv;
        const float4 p0 = *(const float4*)&P[(size_t)n * PSTRIDE + co];
        const float4 p1 = *(const float4*)&P[(size_t)n * PSTRIDE + co + 4];
        r[0] = fmaf(acc[0], sc, p0.x); r[1] = fmaf(acc[1], sc, p0.y);
        r[2] = fmaf(acc[2], sc, p0.z); r[3] = fmaf(acc[3], sc, p0.w);
        r[4] = fmaf(acc[4], sc, p1.x); r[5] = fmaf(acc[5], sc, p1.y);
        r[6] = fmaf(acc[6], sc, p1.z); r[7] = fmaf(acc[7], sc, p1.w);
    }
    if (RELU) {
#pragma unroll
        for (int j = 0; j < 8; ++j) r[j] = fmaxf(r[j], 0.f);
    }
    if (OBF16) {
        // single 16B store per lane; value depends on ALL p-loads -> compiler's
        // s_waitcnt completes every lane's p-load before any overlapping store.
        short8 hv;
#pragma unroll
        for (int j = 0; j < 8; ++j) hv[j] = f2bf(r[j]);
        *(short8*)((unsigned short*)outv + (size_t)n * OSTRIDE + co) = hv;
    } else {
        float4 r0, r1;
        r0.x = r[0]; r0.y = r[1]; r0.z = r[2]; r0.w = r[3];
        r1.x = r[4]; r1.y = r[5]; r1.z = r[6]; r1.w = r[7];
        *(float4*)((float*)outv + (size_t)n * OSTRIDE + co) = r0;
        *(float4*)((float*)outv + (size_t)n * OSTRIDE + co + 4) = r1;
    }
}

// ---------------- launch ----------------

extern "C" void kernel_launch(void* const* d_in, const int* in_sizes, int n_in,
                              void* d_out, int out_size, void* d_ws, size_t ws_size,
                              hipStream_t stream) {
    const float* x   = (const float*)d_in[0];
    const int*   ei  = (const int*)d_in[1];
    const float* W1l = (const float*)d_in[2];
    const float* W1r = (const float*)d_in[3];
    const float* b1  = (const float*)d_in[4];
    const float* W2l = (const float*)d_in[5];
    const float* W2r = (const float*)d_in[6];
    const float* b2  = (const float*)d_in[7];
    float* out = (float*)d_out;

    const int N = in_sizes[0] / CH;
    const int E = in_sizes[1] / 2;
    const int* src = ei;
    const int* dst = ei + E;

    // workspace carve
    char* w = (char*)d_ws;
    size_t o = 0;
    int* cnt     = (int*)(w + o); o += ((size_t)N + 4) * 4;   // cnt[N] = alloc counter
    int* start   = (int*)(w + o); o += (size_t)N * 4;
    int* cursor  = (int*)(w + o); o += (size_t)N * 4;
    int* eidx    = (int*)(w + o); o += (size_t)E * 4;
    short* pw1h  = (short*)(w + o); o += 32768 * 2;
    short* pw1l  = (short*)(w + o); o += 32768 * 2;
    short* pw2h  = (short*)(w + o); o += 16384 * 2;
    short* pw2l  = (short*)(w + o); o += 16384 * 2;
    unsigned short* bufG = (unsigned short*)(w + o); o += (size_t)N * CH * 2;  // g1 / g2 (bf16)
    float* bufP1 = (float*)(w + o); o += (size_t)N * CH * 4;  // p1 fp32; h bf16 embedded (row=512B)
    unsigned short* bufP2 = (unsigned short*)(w + o); o += (size_t)N * 64 * 2; // p2 bf16
    (void)ws_size; (void)n_in; (void)out_size;

    int* counter = cnt + N;
    unsigned short* g1 = bufG;
    float* p1 = bufP1;
    unsigned short* h = (unsigned short*)bufP1;   // row stride 256 ushorts (512 B)
    unsigned short* g2 = bufG;                    // g1 dead after agg1
    unsigned short* p2 = bufP2;

    const int TB = 256;
    const int zb = (N + TB) / TB;           // covers cnt[0..N]
    const int nchunks = (N + 15) / 16;

    hipLaunchKernelGGL(k_zero, dim3(zb), dim3(TB), 0, stream, cnt, N);
    hipLaunchKernelGGL(k_count_pack, dim3(2048), dim3(TB), 0, stream, dst, E, cnt,
                       W1l, W1r, W2l, W2r, pw1h, pw1l, pw2h, pw2l);
    hipLaunchKernelGGL(k_alloc, dim3((N + TB - 1) / TB), dim3(TB), 0, stream,
                       cnt, start, cursor, counter, N);
    hipLaunchKernelGGL(k_fill, dim3(2048), dim3(TB), 0, stream, src, dst, E, cursor, eidx);

    // layer 1
    hipLaunchKernelGGL(k_gemm1, dim3(512), dim3(TB), 0, stream,
                       x, pw1h, pw1l, b1, g1, p1, N, nchunks);
    hipLaunchKernelGGL((k_agg<128, true, false, true, 128, 256>), dim3((N + 15) / 16), dim3(TB), 0, stream,
                       g1, p1, start, cnt, eidx, h, N);
    // layer 2
    hipLaunchKernelGGL(k_gemm2, dim3(1024), dim3(TB), 0, stream,
                       h, pw2h, pw2l, b2, g2, p2, N, nchunks);
    hipLaunchKernelGGL((k_agg<64, false, true, false, 64, 64>), dim3((N + 31) / 32), dim3(TB), 0, stream,
                       g2, p2, start, cnt, eidx, out, N);
}

// Round 9
// 307.783 us; speedup vs baseline: 2.8782x; 1.1215x over previous
//
#include <hip/hip_runtime.h>

// GraphSAGE 2-layer: N=100k, E=800k, 128->128(relu)->64. fp32 in/out.
// R8: atomic-free k_fill. k_count_pack captures each edge's segment rank
// (the atomicAdd return it already computed); k_fill is then a pure
// load/compute/store scatter with no atomic round-trip dependency.
//   gemm1: g1(bf16) = x@W1l, p1(f32) = x@W1r + b1
//   agg1 : h(bf16)  = relu(mean(g1) + p1)        [h in p1's buffer]
//   gemm2: g2(bf16) = h@W2l, p2(bf16) = h@W2r + b2
//   agg2 : out(f32) = mean(g2) + p2

#define CH 128

typedef short short8 __attribute__((ext_vector_type(8)));
typedef float f32x4 __attribute__((ext_vector_type(4)));

__device__ __forceinline__ short f2bf(float x) {        // RNE fp32->bf16
    unsigned u = __float_as_uint(x);
    unsigned r = u + 0x7FFFu + ((u >> 16) & 1u);
    return (short)(r >> 16);
}
__device__ __forceinline__ float b2f(short s) {
    return __uint_as_float(((unsigned)(unsigned short)s) << 16);
}

// ---------------- CSR build ----------------

__global__ __launch_bounds__(256) void k_zero(int* __restrict__ cnt, int N) {
    int i = blockIdx.x * blockDim.x + threadIdx.x;
    if (i <= N) cnt[i] = 0;            // cnt[N] doubles as the alloc counter
}

// B-frag pack: idx = ((ct*4 + kt)*64 + lane)*8 + j ; c = ct*16 + (lane&15),
// k = kt*32 + (lane>>4)*8 + j ; cols = [Wa | Wb] (C2 each).
__device__ __forceinline__ void pack_one(const float* __restrict__ Wa, const float* __restrict__ Wb,
                                         int C2, short* __restrict__ hi, short* __restrict__ lo, int idx) {
    int j    = idx & 7;
    int lane = (idx >> 3) & 63;
    int kt   = (idx >> 9) & 3;
    int ct   = idx >> 11;
    int c = ct * 16 + (lane & 15);
    int k = kt * 32 + (lane >> 4) * 8 + j;
    float w = (c < C2) ? Wa[k * C2 + c] : Wb[k * C2 + (c - C2)];
    short h = f2bf(w);
    hi[idx] = h;
    lo[idx] = f2bf(w - b2f(h));
}

// count degrees (capturing per-edge rank) + pack W panels
__global__ __launch_bounds__(256) void k_count_pack(const int* __restrict__ dst, int E, int* __restrict__ cnt,
                                                    int* __restrict__ rank,
                                                    const float* __restrict__ W1l, const float* __restrict__ W1r,
                                                    const float* __restrict__ W2l, const float* __restrict__ W2r,
                                                    short* __restrict__ pw1h, short* __restrict__ pw1l,
                                                    short* __restrict__ pw2h, short* __restrict__ pw2l) {
    int gid = blockIdx.x * 256 + threadIdx.x;
    if (gid < 32768)      pack_one(W1l, W1r, 128, pw1h, pw1l, gid);
    else if (gid < 49152) pack_one(W2l, W2r, 64, pw2h, pw2l, gid - 32768);
    int stride = gridDim.x * blockDim.x;
    for (int e = gid; e < E; e += stride)
        rank[e] = atomicAdd(&cnt[dst[e]], 1);   // rank = slot within dst segment
}

__global__ __launch_bounds__(256) void k_alloc(const int* __restrict__ cnt, int* __restrict__ start,
                                               int* __restrict__ counter, int N) {
    int n = blockIdx.x * blockDim.x + threadIdx.x;
    int lane = threadIdx.x & 63;
    int d = (n < N) ? cnt[n] : 0;
    int x = d;
#pragma unroll
    for (int o = 1; o < 64; o <<= 1) {
        int y = __shfl_up(x, o);
        if (lane >= o) x += y;
    }
    int total = __shfl(x, 63);
    int base = 0;
    if (lane == 63) base = atomicAdd(counter, total);
    base = __shfl(base, 63);
    int st = base + x - d;
    if (n < N) start[n] = st;
}

// atomic-free scatter: slot precomputed as start[dst] + rank
__global__ __launch_bounds__(256) void k_fill(const int* __restrict__ src, const int* __restrict__ dst,
                                              const int* __restrict__ rank, const int* __restrict__ start,
                                              int E, int* __restrict__ eidx) {
    int stride = gridDim.x * blockDim.x;
    for (int e = blockIdx.x * blockDim.x + threadIdx.x; e < E; e += stride)
        eidx[start[dst[e]] + rank[e]] = src[e];
}

// ---------------- gemm1: persistent-B, fp32 A with RTZ hi / RNE lo split ----------------
// Wave w holds B col-tiles [w*4,(w+1)*4) in regs. 3 MFMA terms.
__global__ __launch_bounds__(256, 2) void k_gemm1(const float* __restrict__ X,
                                                  const short* __restrict__ pHi,
                                                  const short* __restrict__ pLo,
                                                  const float* __restrict__ bias,
                                                  unsigned short* __restrict__ Ga,
                                                  float* __restrict__ Pb,
                                                  int N, int nchunks) {
    constexpr int CTW = 4, CTA = 8;
    const int lane  = threadIdx.x & 63;
    const int wv    = threadIdx.x >> 6;
    const int ncol  = lane & 15;
    const int rbase = (lane >> 4) * 4;
    const int koff  = (lane >> 4) * 8;

    short8 Bh[CTW][4], Bl[CTW][4];
    float bv[CTW];
#pragma unroll
    for (int c = 0; c < CTW; ++c) {
        const int ct = wv * CTW + c;
        bv[c] = (ct >= CTA) ? bias[(ct - CTA) * 16 + ncol] : 0.f;
#pragma unroll
        for (int kt = 0; kt < 4; ++kt) {
            const size_t fo = ((size_t)(ct * 4 + kt) * 64 + lane) * 8;
            Bh[c][kt] = *(const short8*)(pHi + fo);
            Bl[c][kt] = *(const short8*)(pLo + fo);
        }
    }

#pragma unroll 1
    for (int chunk = blockIdx.x; chunk < nchunks; chunk += gridDim.x) {
        const int n0 = chunk * 16;
        short8 Ahi[4], Alo[4];
        {
            int arow = n0 + ncol;
            if (arow >= N) arow = N - 1;
            const float* __restrict__ xr = X + (size_t)arow * CH + koff;
#pragma unroll
            for (int kt = 0; kt < 4; ++kt) {
                const float4 a0 = *(const float4*)(xr + kt * 32);
                const float4 a1 = *(const float4*)(xr + kt * 32 + 4);
                const float av[8] = {a0.x, a0.y, a0.z, a0.w, a1.x, a1.y, a1.z, a1.w};
#pragma unroll
                for (int j = 0; j < 8; ++j) {
                    const unsigned u = __float_as_uint(av[j]);
                    Ahi[kt][j] = (short)(u >> 16);                      // RTZ hi
                    Alo[kt][j] = f2bf(av[j] - __uint_as_float(u & 0xFFFF0000u));
                }
            }
        }

        const int mrow = n0 + rbase;
#pragma unroll
        for (int c = 0; c < CTW; ++c) {
            const int ct = wv * CTW + c;
            f32x4 accA, accB;
            accA[0] = bv[c]; accA[1] = bv[c]; accA[2] = bv[c]; accA[3] = bv[c];
            accB[0] = 0.f;   accB[1] = 0.f;   accB[2] = 0.f;   accB[3] = 0.f;
#pragma unroll
            for (int kt = 0; kt < 4; ++kt) {
                accA = __builtin_amdgcn_mfma_f32_16x16x32_bf16(Ahi[kt], Bh[c][kt], accA, 0, 0, 0);
                accB = __builtin_amdgcn_mfma_f32_16x16x32_bf16(Alo[kt], Bh[c][kt], accB, 0, 0, 0);
                accB = __builtin_amdgcn_mfma_f32_16x16x32_bf16(Ahi[kt], Bl[c][kt], accB, 0, 0, 0);
            }
            if (ct < CTA) {
                const int col = ct * 16 + ncol;
#pragma unroll
                for (int r = 0; r < 4; ++r) {
                    const int n = mrow + r;
                    if (n < N)
                        Ga[(size_t)n * 128 + col] = (unsigned short)f2bf(accA[r] + accB[r]);
                }
            } else {
                const int col = (ct - CTA) * 16 + ncol;
#pragma unroll
                for (int r = 0; r < 4; ++r) {
                    const int n = mrow + r;
                    if (n < N)
                        Pb[(size_t)n * 128 + col] = accA[r] + accB[r];
                }
            }
        }
    }
}

// ---------------- gemm2: persistent-B, EXACT bf16 A (h), 2-term MFMA ----------------
// A rows read from h (bf16, row stride 256 ushorts). g2/p2 outputs bf16.
__global__ __launch_bounds__(256, 4) void k_gemm2(const unsigned short* __restrict__ H,
                                                  const short* __restrict__ pHi,
                                                  const short* __restrict__ pLo,
                                                  const float* __restrict__ bias,
                                                  unsigned short* __restrict__ Ga,
                                                  unsigned short* __restrict__ Pb,
                                                  int N, int nchunks) {
    constexpr int CTW = 2, CTA = 4;
    const int lane  = threadIdx.x & 63;
    const int wv    = threadIdx.x >> 6;
    const int ncol  = lane & 15;
    const int rbase = (lane >> 4) * 4;
    const int koff  = (lane >> 4) * 8;

    short8 Bh[CTW][4], Bl[CTW][4];
    float bv[CTW];
#pragma unroll
    for (int c = 0; c < CTW; ++c) {
        const int ct = wv * CTW + c;
        bv[c] = (ct >= CTA) ? bias[(ct - CTA) * 16 + ncol] : 0.f;
#pragma unroll
        for (int kt = 0; kt < 4; ++kt) {
            const size_t fo = ((size_t)(ct * 4 + kt) * 64 + lane) * 8;
            Bh[c][kt] = *(const short8*)(pHi + fo);
            Bl[c][kt] = *(const short8*)(pLo + fo);
        }
    }

#pragma unroll 1
    for (int chunk = blockIdx.x; chunk < nchunks; chunk += gridDim.x) {
        const int n0 = chunk * 16;
        short8 Ah[4];
        {
            int arow = n0 + ncol;
            if (arow >= N) arow = N - 1;
            const unsigned short* __restrict__ hr = H + (size_t)arow * 256 + koff;
#pragma unroll
            for (int kt = 0; kt < 4; ++kt)
                Ah[kt] = *(const short8*)(hr + kt * 32);   // ch kt*32+koff.. (+8)
        }

        const int mrow = n0 + rbase;
#pragma unroll
        for (int c = 0; c < CTW; ++c) {
            const int ct = wv * CTW + c;
            f32x4 accA, accB;
            accA[0] = bv[c]; accA[1] = bv[c]; accA[2] = bv[c]; accA[3] = bv[c];
            accB[0] = 0.f;   accB[1] = 0.f;   accB[2] = 0.f;   accB[3] = 0.f;
#pragma unroll
            for (int kt = 0; kt < 4; ++kt) {
                accA = __builtin_amdgcn_mfma_f32_16x16x32_bf16(Ah[kt], Bh[c][kt], accA, 0, 0, 0);
                accB = __builtin_amdgcn_mfma_f32_16x16x32_bf16(Ah[kt], Bl[c][kt], accB, 0, 0, 0);
            }
            unsigned short* __restrict__ O = (ct < CTA) ? Ga : Pb;
            const int col = ((ct < CTA) ? ct : ct - CTA) * 16 + ncol;
#pragma unroll
            for (int r = 0; r < 4; ++r) {
                const int n = mrow + r;
                if (n < N)
                    O[(size_t)n * 64 + col] = (unsigned short)f2bf(accA[r] + accB[r]);
            }
        }
    }
}

// ---------------- aggregation: out = [relu](mean_gather(Gbf16) + P) ----------------
// PSTRIDE/OSTRIDE in elements of their storage type.
template <int CHW, bool RELU, bool PBF16, bool OBF16, int PSTRIDE, int OSTRIDE>
__global__ __launch_bounds__(256) void k_agg(const unsigned short* __restrict__ G,
                                             const void* __restrict__ Pv,
                                             const int* __restrict__ start,
                                             const int* __restrict__ cnt,
                                             const int* __restrict__ eidx,
                                             void* __restrict__ outv, int N) {
    constexpr int LPN = CHW / 8;       // lanes per node: 16 / 8
    constexpr int NPB = 256 / LPN;     // nodes per block: 16 / 32
    const int g = threadIdx.x / LPN;
    const int l = threadIdx.x % LPN;
    const int n = blockIdx.x * NPB + g;
    if (n >= N) return;
    const int s0 = start[n];
    const int d  = cnt[n];
    const int* __restrict__ ep = eidx + s0;
    const int co = l * 8;

    float acc[8];
#pragma unroll
    for (int j = 0; j < 8; ++j) acc[j] = 0.f;

    int i = 0;
    for (; i + 4 <= d; i += 4) {
        const int e0 = ep[i], e1 = ep[i + 1], e2 = ep[i + 2], e3 = ep[i + 3];
        const short8 v0 = *(const short8*)&G[(size_t)e0 * CHW + co];
        const short8 v1 = *(const short8*)&G[(size_t)e1 * CHW + co];
        const short8 v2 = *(const short8*)&G[(size_t)e2 * CHW + co];
        const short8 v3 = *(const short8*)&G[(size_t)e3 * CHW + co];
#pragma unroll
        for (int j = 0; j < 8; ++j)
            acc[j] += (b2f(v0[j]) + b2f(v1[j])) + (b2f(v2[j]) + b2f(v3[j]));
    }
    for (; i < d; ++i) {
        const short8 v = *(const short8*)&G[(size_t)ep[i] * CHW + co];
#pragma unroll
        for (int j = 0; j < 8; ++j) acc[j] += b2f(v[j]);
    }

    const float sc = 1.0f / (float)(d > 0 ? d : 1);
    float r[8];
    if (PBF16) {
        const short8 pp = *(const short8*)((const unsigned short*)Pv + (size_t)n * PSTRIDE + co);
#pragma unroll
        for (int j = 0; j < 8; ++j) r[j] = fmaf(acc[j], sc, b2f(pp[j]));
    } else {
        const float* __restrict__ P = (const float*)Pv;
        const float4 p0 = *(const float4*)&P[(size_t)n * PSTRIDE + co];
        const float4 p1 = *(const float4*)&P[(size_t)n * PSTRIDE + co + 4];
        r[0] = fmaf(acc[0], sc, p0.x); r[1] = fmaf(acc[1], sc, p0.y);
        r[2] = fmaf(acc[2], sc, p0.z); r[3] = fmaf(acc[3], sc, p0.w);
        r[4] = fmaf(acc[4], sc, p1.x); r[5] = fmaf(acc[5], sc, p1.y);
        r[6] = fmaf(acc[6], sc, p1.z); r[7] = fmaf(acc[7], sc, p1.w);
    }
    if (RELU) {
#pragma unroll
        for (int j = 0; j < 8; ++j) r[j] = fmaxf(r[j], 0.f);
    }
    if (OBF16) {
        // single 16B store per lane; value depends on ALL p-loads -> compiler's
        // s_waitcnt completes every lane's p-load before any overlapping store.
        short8 hv;
#pragma unroll
        for (int j = 0; j < 8; ++j) hv[j] = f2bf(r[j]);
        *(short8*)((unsigned short*)outv + (size_t)n * OSTRIDE + co) = hv;
    } else {
        float4 r0, r1;
        r0.x = r[0]; r0.y = r[1]; r0.z = r[2]; r0.w = r[3];
        r1.x = r[4]; r1.y = r[5]; r1.z = r[6]; r1.w = r[7];
        *(float4*)((float*)outv + (size_t)n * OSTRIDE + co) = r0;
        *(float4*)((float*)outv + (size_t)n * OSTRIDE + co + 4) = r1;
    }
}

// ---------------- launch ----------------

extern "C" void kernel_launch(void* const* d_in, const int* in_sizes, int n_in,
                              void* d_out, int out_size, void* d_ws, size_t ws_size,
                              hipStream_t stream) {
    const float* x   = (const float*)d_in[0];
    const int*   ei  = (const int*)d_in[1];
    const float* W1l = (const float*)d_in[2];
    const float* W1r = (const float*)d_in[3];
    const float* b1  = (const float*)d_in[4];
    const float* W2l = (const float*)d_in[5];
    const float* W2r = (const float*)d_in[6];
    const float* b2  = (const float*)d_in[7];
    float* out = (float*)d_out;

    const int N = in_sizes[0] / CH;
    const int E = in_sizes[1] / 2;
    const int* src = ei;
    const int* dst = ei + E;

    // workspace carve
    char* w = (char*)d_ws;
    size_t o = 0;
    int* cnt     = (int*)(w + o); o += ((size_t)N + 4) * 4;   // cnt[N] = alloc counter
    int* start   = (int*)(w + o); o += (size_t)N * 4;
    int* rank    = (int*)(w + o); o += (size_t)E * 4;         // per-edge segment rank
    int* eidx    = (int*)(w + o); o += (size_t)E * 4;
    short* pw1h  = (short*)(w + o); o += 32768 * 2;
    short* pw1l  = (short*)(w + o); o += 32768 * 2;
    short* pw2h  = (short*)(w + o); o += 16384 * 2;
    short* pw2l  = (short*)(w + o); o += 16384 * 2;
    unsigned short* bufG = (unsigned short*)(w + o); o += (size_t)N * CH * 2;  // g1 / g2 (bf16)
    float* bufP1 = (float*)(w + o); o += (size_t)N * CH * 4;  // p1 fp32; h bf16 embedded (row=512B)
    unsigned short* bufP2 = (unsigned short*)(w + o); o += (size_t)N * 64 * 2; // p2 bf16
    (void)ws_size; (void)n_in; (void)out_size;

    int* counter = cnt + N;
    unsigned short* g1 = bufG;
    float* p1 = bufP1;
    unsigned short* h = (unsigned short*)bufP1;   // row stride 256 ushorts (512 B)
    unsigned short* g2 = bufG;                    // g1 dead after agg1
    unsigned short* p2 = bufP2;

    const int TB = 256;
    const int zb = (N + TB) / TB;           // covers cnt[0..N]
    const int nchunks = (N + 15) / 16;

    hipLaunchKernelGGL(k_zero, dim3(zb), dim3(TB), 0, stream, cnt, N);
    hipLaunchKernelGGL(k_count_pack, dim3(2048), dim3(TB), 0, stream, dst, E, cnt, rank,
                       W1l, W1r, W2l, W2r, pw1h, pw1l, pw2h, pw2l);
    hipLaunchKernelGGL(k_alloc, dim3((N + TB - 1) / TB), dim3(TB), 0, stream,
                       cnt, start, counter, N);
    hipLaunchKernelGGL(k_fill, dim3(2048), dim3(TB), 0, stream, src, dst, rank, start, E, eidx);

    // layer 1
    hipLaunchKernelGGL(k_gemm1, dim3(512), dim3(TB), 0, stream,
                       x, pw1h, pw1l, b1, g1, p1, N, nchunks);
    hipLaunchKernelGGL((k_agg<128, true, false, true, 128, 256>), dim3((N + 15) / 16), dim3(TB), 0, stream,
                       g1, p1, start, cnt, eidx, h, N);
    // layer 2
    hipLaunchKernelGGL(k_gemm2, dim3(1024), dim3(TB), 0, stream,
                       h, pw2h, pw2l, b2, g2, p2, N, nchunks);
    hipLaunchKernelGGL((k_agg<64, false, true, false, 64, 64>), dim3((N + 31) / 32), dim3(TB), 0, stream,
                       g2, p2, start, cnt, eidx, out, N);
}